// Round 3
// baseline (292.836 us; speedup 1.0000x reference)
//
#include <hip/hip_runtime.h>

// Feature dims fixed by the problem
constexpr int FIN = 64;   // input features
constexpr int FH  = 64;   // hidden
constexpr int FO  = 16;   // output

// edge_index arrives as int32 (harness integer convention), flat [2][E]:
// src = ei[e], dst = ei[e + E].

// Bucket sort parameters: bucket = dst >> 7 (128 nodes per bucket).
constexpr int BSH      = 7;
constexpr int BW       = 1 << BSH;  // 128 nodes / bucket
constexpr int NBUCK    = 1024;      // covers N up to 131072
// ONE chunk size shared by hist and binning. 4096 edges/chunk -> 391 chunks:
// enough blocks that the load->atomic->store chains are hidden by TLP
// (16384 gave only 98 blocks -> <1 block/CU -> 27 us serial-chain stragglers).
constexpr int EPB      = 4096;

// GEMM x-tile LDS stride: 68 floats (pad 64+4) so the 4-row-strided compute
// reads alias only 2-way on banks (2-way is free on CDNA4).
constexpr int XSTR     = 68;

// bf16 helpers (manual RNE; exact expand)
__device__ inline unsigned short f2bf(float f) {
    unsigned u = __float_as_uint(f);
    return (unsigned short)((u + 0x7FFFu + ((u >> 16) & 1u)) >> 16);
}
__device__ inline float bf2f(unsigned short h) {
    return __uint_as_float((unsigned)h << 16);
}
__device__ inline float4 bf4_to_f4(ushort4 u) {
    float4 f;
    f.x = bf2f(u.x); f.y = bf2f(u.y); f.z = bf2f(u.z); f.w = bf2f(u.w);
    return f;
}

// ---------------------------------------------------------------------------
// Kernel: dst-bucket histogram + per-node degree. One block per 4K-edge
// chunk; 8-deep batched loads (independent) then 8 atomic chains. Stores the
// per-chunk hist (gchist, ushort) and accumulates global bucket counts and
// per-node degrees (fire-and-forget global atomics, spread over N addrs).
// ---------------------------------------------------------------------------
__launch_bounds__(256)
__global__ void hist_kernel(const int* __restrict__ ei, int E,
                            int* __restrict__ bcnt,
                            unsigned short* __restrict__ gchist,
                            int* __restrict__ deg) {
    __shared__ int lh[NBUCK];
    int t = threadIdx.x;
    for (int i = t; i < NBUCK; i += 256) lh[i] = 0;
    __syncthreads();
    int base = blockIdx.x * EPB;
    int lim  = min(E, base + EPB);
    for (int e0 = base + t; e0 < lim; e0 += 2048) {
        int dd[8];
        #pragma unroll
        for (int q = 0; q < 8; ++q) {
            int e = e0 + q * 256;
            dd[q] = (e < lim) ? ei[E + e] : -1;
        }
        #pragma unroll
        for (int q = 0; q < 8; ++q) {
            if (dd[q] >= 0) {
                atomicAdd(&lh[dd[q] >> BSH], 1);
                atomicAdd(&deg[dd[q]], 1);          // no-return, off critical path
            }
        }
    }
    __syncthreads();
    unsigned short* gh = gchist + (size_t)blockIdx.x * NBUCK;
    for (int b = t; b < NBUCK; b += 256) {
        int c = lh[b];
        gh[b] = (unsigned short)c;                  // c <= EPB=4096, fits ushort
        if (c > 0) atomicAdd(&bcnt[b], c);
    }
}

// ---------------------------------------------------------------------------
// Kernel: exclusive scan of bucket counts -> bbase[NBUCK+1], then the
// per-(chunk,bucket) deterministic write bases (thread t owns bucket t):
// gbase[c][t] = bbase[t] + sum_{c'<c} gchist[c'][t].
// Single block of 1024 threads. Also writes offs[N] = E.
// ---------------------------------------------------------------------------
__launch_bounds__(1024)
__global__ void bucket_scan_kernel(const int* __restrict__ bcnt, int* __restrict__ bbase,
                                   const unsigned short* __restrict__ gchist,
                                   int* __restrict__ gbase,
                                   int NCH, int* __restrict__ offs, int N, int E) {
    __shared__ int s[NBUCK];
    int t = threadIdx.x;
    int v = bcnt[t];
    s[t] = v;
    __syncthreads();
    for (int d = 1; d < NBUCK; d <<= 1) {
        int u = (t >= d) ? s[t - d] : 0;
        __syncthreads();
        s[t] += u;
        __syncthreads();
    }
    int ex = s[t] - v;
    bbase[t] = ex;
    if (t == NBUCK - 1) {
        bbase[NBUCK] = s[t];   // == E
        offs[N] = E;
    }
    // per-chunk bases: coalesced along t; loads independent -> deep unroll
    int run = ex;
    #pragma unroll 16
    for (int c = 0; c < NCH; ++c) {
        gbase[(size_t)c * NBUCK + t] = run;
        run += (int)gchist[(size_t)c * NBUCK + t];
    }
}

// ---------------------------------------------------------------------------
// Binning device body: cursor row comes precomputed from gbase -> single
// pass, LDS atomics only. 8-deep batched: 8 independent (d,src) loads, then
// 8 atomic+store chains overlapped. EPB=4096 -> exactly 2 batches/thread.
// Packed word: src | (dst & 127) << 17 (N < 2^17).
// ---------------------------------------------------------------------------
__device__ inline void binning_body(const int* __restrict__ ei, int E, int chunk,
                                    const int* __restrict__ gbase,
                                    unsigned* __restrict__ ebuf, int* lh) {
    int t = threadIdx.x;
    const int* gb = gbase + (size_t)chunk * NBUCK;
    for (int i = t; i < NBUCK; i += 256) lh[i] = gb[i];
    __syncthreads();
    int base = chunk * EPB;
    int lim  = min(E, base + EPB);
    for (int e0 = base + t; e0 < lim; e0 += 2048) {
        int dd[8], ss[8];
        #pragma unroll
        for (int q = 0; q < 8; ++q) {
            int e = e0 + q * 256;
            if (e < lim) { dd[q] = ei[E + e]; ss[q] = ei[e]; } else dd[q] = -1;
        }
        #pragma unroll
        for (int q = 0; q < 8; ++q) {
            if (dd[q] >= 0) {
                int pos = atomicAdd(&lh[dd[q] >> BSH], 1);
                ebuf[pos] = (unsigned)ss[q] | ((unsigned)(dd[q] & (BW - 1)) << 17);
            }
        }
    }
}

__launch_bounds__(256)
__global__ void binning_kernel(const int* __restrict__ ei, int E,
                               const int* __restrict__ gbase, unsigned* __restrict__ ebuf) {
    __shared__ int lh[NBUCK];
    binning_body(ei, E, blockIdx.x, gbase, ebuf, lh);
}

// ---------------------------------------------------------------------------
// Fused kernel: blocks [0, NBIN) do binning; blocks [NBIN, NBIN+G1T) compute
// hsb = bf16(dinv[row] * (x @ W1)) -- PRE-SCALED by the row's dinv so the
// agg1 gather loop needs no dinv[src] loads at all. dinv comes from deg
// (written by hist): this block also computes and stores dinv[] for its rows.
// W1 and the 64x64 x-tile staged in LDS; 4x4 microkernel per thread.
// ---------------------------------------------------------------------------
__launch_bounds__(256, 4)
__global__ void gemm1_binning_kernel(const float* __restrict__ x, const float* __restrict__ W1,
                                     unsigned short* __restrict__ hsb,
                                     const int* __restrict__ ei, int E,
                                     const int* __restrict__ gbase, unsigned* __restrict__ ebuf,
                                     const int* __restrict__ deg, float* __restrict__ dinv,
                                     int N, int NBIN) {
    __shared__ float smem[FIN * FH + 64 * XSTR + 64];  // 34 KB: Ws + Xs + dinv_s | lh
    int tid = threadIdx.x;
    if ((int)blockIdx.x < NBIN) {
        binning_body(ei, E, (int)blockIdx.x, gbase, ebuf, (int*)smem);
        return;
    }
    // ---- GEMM phase ----
    float* Ws   = smem;                    // [64][64] row-major (k, col)
    float* Xs   = smem + FIN * FH;         // [64][XSTR] row-major (row, k), padded
    float* dvs  = smem + FIN * FH + 64 * XSTR;  // [64] per-row dinv
    int rowBase = ((int)blockIdx.x - NBIN) * 64;
    {
        const float4* W14 = (const float4*)W1;
        float4* Ws4 = (float4*)Ws;
        #pragma unroll
        for (int i = tid; i < 1024; i += 256) Ws4[i] = W14[i];
        const float4* x4 = (const float4*)x;
        #pragma unroll
        for (int i = tid; i < 1024; i += 256) {
            int row = i >> 4, kq = i & 15;
            int gr = min(rowBase + row, N - 1);    // clamp: loads never fault
            *(float4*)&Xs[row * XSTR + kq * 4] = x4[(size_t)gr * 16 + kq];
        }
        if (tid < 64) {
            int gr = min(rowBase + tid, N - 1);
            float dv = rsqrtf((float)(deg[gr] + 1));
            dvs[tid] = dv;
            if (rowBase + tid < N) dinv[rowBase + tid] = dv;
        }
    }
    __syncthreads();
    int cg = tid & 15;                 // col group: cols cg*4..+3
    int rg = tid >> 4;                 // row group: rows rg*4..+3
    int r0 = rowBase + rg * 4;
    float4 acc0 = {0,0,0,0}, acc1 = {0,0,0,0}, acc2 = {0,0,0,0}, acc3 = {0,0,0,0};
    #pragma unroll 2
    for (int kc = 0; kc < 16; ++kc) {
        float4 xa0 = *(const float4*)&Xs[(rg * 4 + 0) * XSTR + kc * 4];
        float4 xa1 = *(const float4*)&Xs[(rg * 4 + 1) * XSTR + kc * 4];
        float4 xa2 = *(const float4*)&Xs[(rg * 4 + 2) * XSTR + kc * 4];
        float4 xa3 = *(const float4*)&Xs[(rg * 4 + 3) * XSTR + kc * 4];
        const float* xa0f = (const float*)&xa0;
        const float* xa1f = (const float*)&xa1;
        const float* xa2f = (const float*)&xa2;
        const float* xa3f = (const float*)&xa3;
        #pragma unroll
        for (int j = 0; j < 4; ++j) {
            float4 wv = *(const float4*)&Ws[(kc * 4 + j) * FH + cg * 4];
            float v0 = xa0f[j], v1 = xa1f[j], v2 = xa2f[j], v3 = xa3f[j];
            acc0.x = fmaf(v0, wv.x, acc0.x); acc0.y = fmaf(v0, wv.y, acc0.y);
            acc0.z = fmaf(v0, wv.z, acc0.z); acc0.w = fmaf(v0, wv.w, acc0.w);
            acc1.x = fmaf(v1, wv.x, acc1.x); acc1.y = fmaf(v1, wv.y, acc1.y);
            acc1.z = fmaf(v1, wv.z, acc1.z); acc1.w = fmaf(v1, wv.w, acc1.w);
            acc2.x = fmaf(v2, wv.x, acc2.x); acc2.y = fmaf(v2, wv.y, acc2.y);
            acc2.z = fmaf(v2, wv.z, acc2.z); acc2.w = fmaf(v2, wv.w, acc2.w);
            acc3.x = fmaf(v3, wv.x, acc3.x); acc3.y = fmaf(v3, wv.y, acc3.y);
            acc3.z = fmaf(v3, wv.z, acc3.z); acc3.w = fmaf(v3, wv.w, acc3.w);
        }
    }
    float s0 = dvs[rg * 4 + 0], s1 = dvs[rg * 4 + 1];
    float s2 = dvs[rg * 4 + 2], s3 = dvs[rg * 4 + 3];
    ushort4* hsb4 = (ushort4*)hsb;
    if (r0 + 0 < N) hsb4[(size_t)(r0 + 0) * 16 + cg] =
        make_ushort4(f2bf(acc0.x*s0), f2bf(acc0.y*s0), f2bf(acc0.z*s0), f2bf(acc0.w*s0));
    if (r0 + 1 < N) hsb4[(size_t)(r0 + 1) * 16 + cg] =
        make_ushort4(f2bf(acc1.x*s1), f2bf(acc1.y*s1), f2bf(acc1.z*s1), f2bf(acc1.w*s1));
    if (r0 + 2 < N) hsb4[(size_t)(r0 + 2) * 16 + cg] =
        make_ushort4(f2bf(acc2.x*s2), f2bf(acc2.y*s2), f2bf(acc2.z*s2), f2bf(acc2.w*s2));
    if (r0 + 3 < N) hsb4[(size_t)(r0 + 3) * 16 + cg] =
        make_ushort4(f2bf(acc3.x*s3), f2bf(acc3.y*s3), f2bf(acc3.z*s3), f2bf(acc3.w*s3));
}

// ---------------------------------------------------------------------------
// Kernel: per-bucket CSR build + offs. One block per bucket; 8-deep batched
// passes; all csr stores land in the block's own contiguous region.
// ---------------------------------------------------------------------------
__launch_bounds__(256)
__global__ void bucket_csr_kernel(const unsigned* __restrict__ ebuf,
                                  const int* __restrict__ bbase,
                                  int* __restrict__ csr, int* __restrict__ offs, int N) {
    __shared__ int cnt[BW], sc[BW], cur[BW];
    int t = threadIdx.x;
    int b = blockIdx.x;
    if (t < BW) cnt[t] = 0;
    __syncthreads();
    int beg = bbase[b], end = bbase[b + 1];
    for (int i0 = beg + t; i0 < end; i0 += 2048) {
        unsigned ww[8];
        #pragma unroll
        for (int q = 0; q < 8; ++q) {
            int i = i0 + q * 256;
            ww[q] = (i < end) ? ebuf[i] : 0xFFFFFFFFu;   // valid entries < 2^24
        }
        #pragma unroll
        for (int q = 0; q < 8; ++q)
            if (ww[q] != 0xFFFFFFFFu) atomicAdd(&cnt[ww[q] >> 17], 1);
    }
    __syncthreads();
    if (t < BW) sc[t] = cnt[t];
    __syncthreads();
    for (int d = 1; d < BW; d <<= 1) {
        int u = (t < BW && t >= d) ? sc[t - d] : 0;
        __syncthreads();
        if (t < BW) sc[t] += u;
        __syncthreads();
    }
    int nodeBase = b << BSH;
    if (t < BW) {
        int node = nodeBase + t;
        int ex = beg + sc[t] - cnt[t];
        cur[t] = ex;
        if (node < N) offs[node] = ex;
    }
    __syncthreads();
    for (int i0 = beg + t; i0 < end; i0 += 2048) {
        unsigned ww[8];
        #pragma unroll
        for (int q = 0; q < 8; ++q) {
            int i = i0 + q * 256;
            ww[q] = (i < end) ? ebuf[i] : 0xFFFFFFFFu;
        }
        #pragma unroll
        for (int q = 0; q < 8; ++q) {
            if (ww[q] != 0xFFFFFFFFu) {
                int pos = atomicAdd(&cur[ww[q] >> 17], 1);
                csr[pos] = (int)(ww[q] & 0x1FFFF);
            }
        }
    }
}

// ---------------------------------------------------------------------------
// Kernel: layer-1 PULL aggregation (hsb is PRE-SCALED by dinv[src] -> the
// loop is pure csr->gather->add) fused with finalize1 + GEMM2; writes hs2
// pre-scaled as bf16. 16 nodes/block; 16 lanes/node, lane owns 4 features.
// ---------------------------------------------------------------------------
__launch_bounds__(256)
__global__ void agg1_gemm2_kernel(const unsigned short* __restrict__ hsb,
                                  const int* __restrict__ csr,
                                  const int* __restrict__ offs, const float* __restrict__ dinv,
                                  const float* __restrict__ b1, const float* __restrict__ W2,
                                  unsigned short* __restrict__ hs2b, int N) {
    __shared__ float W2s[FH * FO];       // 4 KB
    __shared__ float h1s[16][68];        // 68-float row stride (16B-aligned, non-pow2)
    const ushort4* hs4 = (const ushort4*)hsb;   // 16 ushort4 per row
    int tid = threadIdx.x;
    for (int i = tid; i < FH * FO; i += 256) W2s[i] = W2[i];
    int g = tid >> 4, l = tid & 15;
    int n = blockIdx.x * 16 + g;
    if (n < N) {
        float di_n = dinv[n];
        float4 acc = bf4_to_f4(hs4[(size_t)n * 16 + l]);   // self (pre-scaled)
        int j = offs[n], end = offs[n + 1];
        for (; j + 7 < end; j += 8) {              // 8 gathers in flight
            int s0 = csr[j],     s1 = csr[j + 1], s2 = csr[j + 2], s3 = csr[j + 3];
            int s4 = csr[j + 4], s5 = csr[j + 5], s6 = csr[j + 6], s7 = csr[j + 7];
            float4 a0 = bf4_to_f4(hs4[(size_t)s0 * 16 + l]);
            float4 a1 = bf4_to_f4(hs4[(size_t)s1 * 16 + l]);
            float4 a2 = bf4_to_f4(hs4[(size_t)s2 * 16 + l]);
            float4 a3 = bf4_to_f4(hs4[(size_t)s3 * 16 + l]);
            float4 a4 = bf4_to_f4(hs4[(size_t)s4 * 16 + l]);
            float4 a5 = bf4_to_f4(hs4[(size_t)s5 * 16 + l]);
            float4 a6 = bf4_to_f4(hs4[(size_t)s6 * 16 + l]);
            float4 a7 = bf4_to_f4(hs4[(size_t)s7 * 16 + l]);
            acc.x += ((a0.x + a1.x) + (a2.x + a3.x)) + ((a4.x + a5.x) + (a6.x + a7.x));
            acc.y += ((a0.y + a1.y) + (a2.y + a3.y)) + ((a4.y + a5.y) + (a6.y + a7.y));
            acc.z += ((a0.z + a1.z) + (a2.z + a3.z)) + ((a4.z + a5.z) + (a6.z + a7.z));
            acc.w += ((a0.w + a1.w) + (a2.w + a3.w)) + ((a4.w + a5.w) + (a6.w + a7.w));
        }
        for (; j + 1 < end; j += 2) {
            int s0 = csr[j], s1 = csr[j + 1];
            float4 a0 = bf4_to_f4(hs4[(size_t)s0 * 16 + l]);
            float4 a1 = bf4_to_f4(hs4[(size_t)s1 * 16 + l]);
            acc.x += a0.x + a1.x; acc.y += a0.y + a1.y;
            acc.z += a0.z + a1.z; acc.w += a0.w + a1.w;
        }
        if (j < end) {
            float4 a0 = bf4_to_f4(hs4[(size_t)csr[j] * 16 + l]);
            acc.x += a0.x; acc.y += a0.y; acc.z += a0.z; acc.w += a0.w;
        }
        float4 bb = ((const float4*)b1)[l];
        float4 h;
        h.x = fmaxf(fmaf(di_n, acc.x, bb.x), 0.f);
        h.y = fmaxf(fmaf(di_n, acc.y, bb.y), 0.f);
        h.z = fmaxf(fmaf(di_n, acc.z, bb.z), 0.f);
        h.w = fmaxf(fmaf(di_n, acc.w, bb.w), 0.f);
        *((float4*)&h1s[g][l * 4]) = h;
    }
    __syncthreads();
    int r = tid >> 4, o = tid & 15;     // 16 rows x 16 out-cols
    int n2 = blockIdx.x * 16 + r;
    if (n2 < N) {
        float acc = 0.f;
        #pragma unroll
        for (int jj = 0; jj < FH; ++jj)
            acc = fmaf(h1s[r][jj], W2s[jj * FO + o], acc);
        hs2b[(size_t)n2 * FO + o] = f2bf(acc * dinv[n2]);   // pre-scaled bf16
    }
}

// ---------------------------------------------------------------------------
// Kernel: layer-2 PULL aggregation (8 gathers in flight) + bias + log_softmax.
// hs2b table is 3.2 MB -> fits per-XCD L2; gathers are 2B/lane.
// ---------------------------------------------------------------------------
__launch_bounds__(256)
__global__ void agg2_softmax_kernel(const unsigned short* __restrict__ hs2b,
                                    const int* __restrict__ csr,
                                    const int* __restrict__ offs, const float* __restrict__ dinv,
                                    const float* __restrict__ b2, float* __restrict__ out, int N) {
    int tid = threadIdx.x;
    int g = tid >> 4, o = tid & 15;
    int n = blockIdx.x * 16 + g;
    float v = 0.f;
    if (n < N) {
        float acc = bf2f(hs2b[(size_t)n * 16 + o]);    // self loop (pre-scaled)
        int j = offs[n], end = offs[n + 1];
        for (; j + 7 < end; j += 8) {
            int s0 = csr[j],     s1 = csr[j + 1], s2 = csr[j + 2], s3 = csr[j + 3];
            int s4 = csr[j + 4], s5 = csr[j + 5], s6 = csr[j + 6], s7 = csr[j + 7];
            float t0 = bf2f(hs2b[(size_t)s0 * 16 + o]) + bf2f(hs2b[(size_t)s1 * 16 + o]);
            float t1 = bf2f(hs2b[(size_t)s2 * 16 + o]) + bf2f(hs2b[(size_t)s3 * 16 + o]);
            float t2 = bf2f(hs2b[(size_t)s4 * 16 + o]) + bf2f(hs2b[(size_t)s5 * 16 + o]);
            float t3 = bf2f(hs2b[(size_t)s6 * 16 + o]) + bf2f(hs2b[(size_t)s7 * 16 + o]);
            acc += (t0 + t1) + (t2 + t3);
        }
        for (; j < end; ++j) acc += bf2f(hs2b[(size_t)csr[j] * 16 + o]);
        v = fmaf(dinv[n], acc, b2[o]);
    }
    float m = v;
    #pragma unroll
    for (int s = 8; s >= 1; s >>= 1) m = fmaxf(m, __shfl_xor(m, s, 64));
    float ex = __expf(v - m);
    float sum = ex;
    #pragma unroll
    for (int s = 8; s >= 1; s >>= 1) sum += __shfl_xor(sum, s, 64);
    if (n < N) out[(size_t)n * FO + o] = v - m - __logf(sum);
}

// ---------------------------------------------------------------------------
extern "C" void kernel_launch(void* const* d_in, const int* in_sizes, int n_in,
                              void* d_out, int out_size, void* d_ws, size_t ws_size,
                              hipStream_t stream) {
    const float* x  = (const float*)d_in[0];
    const int*   ei = (const int*)d_in[1];     // int32
    const float* W1 = (const float*)d_in[2];
    const float* b1 = (const float*)d_in[3];
    const float* W2 = (const float*)d_in[4];
    const float* b2 = (const float*)d_in[5];
    float* out = (float*)d_out;

    const int N = in_sizes[0] / FIN;
    const int E = in_sizes[1] / 2;
    const int NCH  = (E + EPB - 1) / EPB;            // hist/binning chunks
    const int NB4  = (N + BW - 1) / BW;              // buckets actually used
    const int G1T  = (N + 63) / 64;                  // gemm 64-row tiles
    const int GA   = (N + 15) / 16;                  // agg blocks

    char* ws = (char*)d_ws;
    size_t off = 0;
    auto alloc = [&](size_t bytes) -> void* {
        off = (off + 255) & ~(size_t)255;
        void* p = ws + off;
        off += bytes;
        return p;
    };
    float*          dinv   = (float*)alloc((size_t)N * 4);               //  0.4 MB
    int*            deg    = (int*)alloc((size_t)N * 4);                 //  0.4 MB
    unsigned short* hsb    = (unsigned short*)alloc((size_t)N * FH * 2); // 12.8 MB
    unsigned short* hs2b   = (unsigned short*)alloc((size_t)N * FO * 2); //  3.2 MB
    int*            offs   = (int*)alloc((size_t)(N + 1) * 4);           //  0.4 MB
    int*            bcnt   = (int*)alloc(NBUCK * 4);
    int*            bbase  = (int*)alloc((NBUCK + 1) * 4);
    unsigned short* gchist = (unsigned short*)alloc((size_t)NCH * NBUCK * 2); // 0.8 MB
    int*            gbase  = (int*)alloc((size_t)NCH * NBUCK * 4);       //  1.6 MB
    // ebuf + csr (2*E ints = 12.8 MB): in ws if it fits, else alias the x
    // input buffer (25.6 MB, dead after the gemm phase; harness restores d_in
    // before every launch; ws_size constant -> capture-stable branch).
    unsigned* ebuf;
    int*      csr;
    bool ws_fits = (ws_size >= off + 512 + (size_t)E * 8);
    if (ws_fits) {
        ebuf = (unsigned*)alloc((size_t)E * 4);
        csr  = (int*)     alloc((size_t)E * 4);
    } else {
        ebuf = (unsigned*)x;
        csr  = (int*)x + E;
    }

    hipMemsetAsync(bcnt, 0, NBUCK * 4, stream);
    hipMemsetAsync(deg, 0, (size_t)N * 4, stream);

    hist_kernel<<<NCH, 256, 0, stream>>>(ei, E, bcnt, gchist, deg);
    bucket_scan_kernel<<<1, NBUCK, 0, stream>>>(bcnt, bbase, gchist, gbase, NCH,
                                                offs, N, E);
    if (ws_fits) {
        // Overlap: binning blocks first, gemm blocks backfill.
        gemm1_binning_kernel<<<NCH + G1T, 256, 0, stream>>>(x, W1, hsb, ei, E,
                                                            gbase, ebuf, deg, dinv,
                                                            N, NCH);
    } else {
        // ebuf aliases x: gemm must fully precede binning.
        gemm1_binning_kernel<<<G1T, 256, 0, stream>>>(x, W1, hsb, ei, E,
                                                      gbase, ebuf, deg, dinv, N, 0);
        binning_kernel<<<NCH, 256, 0, stream>>>(ei, E, gbase, ebuf);
    }
    bucket_csr_kernel<<<NB4, 256, 0, stream>>>(ebuf, bbase, csr, offs, N);
    agg1_gemm2_kernel<<<GA, 256, 0, stream>>>(hsb, csr, offs, dinv, b1, W2, hs2b, N);
    agg2_softmax_kernel<<<GA, 256, 0, stream>>>(hs2b, csr, offs, dinv, b2, out, N);
}

// Round 4
// 244.316 us; speedup vs baseline: 1.1986x; 1.1986x over previous
//
#include <hip/hip_runtime.h>

// Feature dims fixed by the problem
constexpr int FIN = 64;   // input features
constexpr int FH  = 64;   // hidden
constexpr int FO  = 16;   // output

// edge_index arrives as int32 (harness integer convention), flat [2][E]:
// src = ei[e], dst = ei[e + E].

// Bucket sort parameters: bucket = dst >> 7 (128 nodes per bucket).
constexpr int BSH      = 7;
constexpr int BW       = 1 << BSH;  // 128 nodes / bucket
constexpr int NBUCK    = 1024;      // covers N up to 131072
// ONE chunk size shared by hist and binning. 4096 edges/chunk -> 391 chunks:
// enough blocks that the load->atomic->store chains are hidden by TLP
// (16384 gave only 98 blocks -> <1 block/CU -> 27 us serial-chain stragglers).
constexpr int EPB      = 4096;

// GEMM x-tile LDS stride: 68 floats (pad 64+4) so the 4-row-strided compute
// reads alias only 2-way on banks (2-way is free on CDNA4).
constexpr int XSTR     = 68;

// bf16 helpers (manual RNE; exact expand)
__device__ inline unsigned short f2bf(float f) {
    unsigned u = __float_as_uint(f);
    return (unsigned short)((u + 0x7FFFu + ((u >> 16) & 1u)) >> 16);
}
__device__ inline float bf2f(unsigned short h) {
    return __uint_as_float((unsigned)h << 16);
}
__device__ inline float4 bf4_to_f4(ushort4 u) {
    float4 f;
    f.x = bf2f(u.x); f.y = bf2f(u.y); f.z = bf2f(u.z); f.w = bf2f(u.w);
    return f;
}

// ---------------------------------------------------------------------------
// Kernel: dst-bucket histogram. One block per 4K-edge chunk; 8-deep batched
// loads (independent) then 8 LDS-atomic chains. Stores the per-chunk hist
// (gchist, ushort) and accumulates global bucket counts. NO per-node degree
// atomics (round-3 lesson: 1.6M random global atomics = 52 MB HBM write,
// 73 us of pure atomic drain).
// ---------------------------------------------------------------------------
__launch_bounds__(256)
__global__ void hist_kernel(const int* __restrict__ ei, int E,
                            int* __restrict__ bcnt,
                            unsigned short* __restrict__ gchist) {
    __shared__ int lh[NBUCK];
    int t = threadIdx.x;
    for (int i = t; i < NBUCK; i += 256) lh[i] = 0;
    __syncthreads();
    int base = blockIdx.x * EPB;
    int lim  = min(E, base + EPB);
    for (int e0 = base + t; e0 < lim; e0 += 2048) {
        int dd[8];
        #pragma unroll
        for (int q = 0; q < 8; ++q) {
            int e = e0 + q * 256;
            dd[q] = (e < lim) ? ei[E + e] : -1;
        }
        #pragma unroll
        for (int q = 0; q < 8; ++q)
            if (dd[q] >= 0) atomicAdd(&lh[dd[q] >> BSH], 1);
    }
    __syncthreads();
    unsigned short* gh = gchist + (size_t)blockIdx.x * NBUCK;
    for (int b = t; b < NBUCK; b += 256) {
        int c = lh[b];
        gh[b] = (unsigned short)c;                  // c <= EPB=4096, fits ushort
        if (c > 0) atomicAdd(&bcnt[b], c);
    }
}

// ---------------------------------------------------------------------------
// Kernel: exclusive scan of bucket counts -> bbase[NBUCK+1], then the
// per-(chunk,bucket) deterministic write bases (thread t owns bucket t):
// gbase[c][t] = bbase[t] + sum_{c'<c} gchist[c'][t].
// Single block of 1024 threads. Also writes offs[N] = E.
// ---------------------------------------------------------------------------
__launch_bounds__(1024)
__global__ void bucket_scan_kernel(const int* __restrict__ bcnt, int* __restrict__ bbase,
                                   const unsigned short* __restrict__ gchist,
                                   int* __restrict__ gbase,
                                   int NCH, int* __restrict__ offs, int N, int E) {
    __shared__ int s[NBUCK];
    int t = threadIdx.x;
    int v = bcnt[t];
    s[t] = v;
    __syncthreads();
    for (int d = 1; d < NBUCK; d <<= 1) {
        int u = (t >= d) ? s[t - d] : 0;
        __syncthreads();
        s[t] += u;
        __syncthreads();
    }
    int ex = s[t] - v;
    bbase[t] = ex;
    if (t == NBUCK - 1) {
        bbase[NBUCK] = s[t];   // == E
        offs[N] = E;
    }
    // per-chunk bases: coalesced along t; loads independent -> deep unroll
    int run = ex;
    #pragma unroll 16
    for (int c = 0; c < NCH; ++c) {
        gbase[(size_t)c * NBUCK + t] = run;
        run += (int)gchist[(size_t)c * NBUCK + t];
    }
}

// ---------------------------------------------------------------------------
// Binning device body: cursor row comes precomputed from gbase -> single
// pass, LDS atomics only. 8-deep batched: 8 independent (d,src) loads, then
// 8 atomic+store chains overlapped. EPB=4096 -> exactly 2 batches/thread.
// Packed word: src | (dst & 127) << 17 (N < 2^17).
// ---------------------------------------------------------------------------
__device__ inline void binning_body(const int* __restrict__ ei, int E, int chunk,
                                    const int* __restrict__ gbase,
                                    unsigned* __restrict__ ebuf, int* lh) {
    int t = threadIdx.x;
    const int* gb = gbase + (size_t)chunk * NBUCK;
    for (int i = t; i < NBUCK; i += 256) lh[i] = gb[i];
    __syncthreads();
    int base = chunk * EPB;
    int lim  = min(E, base + EPB);
    for (int e0 = base + t; e0 < lim; e0 += 2048) {
        int dd[8], ss[8];
        #pragma unroll
        for (int q = 0; q < 8; ++q) {
            int e = e0 + q * 256;
            if (e < lim) { dd[q] = ei[E + e]; ss[q] = ei[e]; } else dd[q] = -1;
        }
        #pragma unroll
        for (int q = 0; q < 8; ++q) {
            if (dd[q] >= 0) {
                int pos = atomicAdd(&lh[dd[q] >> BSH], 1);
                ebuf[pos] = (unsigned)ss[q] | ((unsigned)(dd[q] & (BW - 1)) << 17);
            }
        }
    }
}

__launch_bounds__(256)
__global__ void binning_kernel(const int* __restrict__ ei, int E,
                               const int* __restrict__ gbase, unsigned* __restrict__ ebuf) {
    __shared__ int lh[NBUCK];
    binning_body(ei, E, blockIdx.x, gbase, ebuf, lh);
}

// ---------------------------------------------------------------------------
// Fused kernel: blocks [0, NBIN) do binning (latency-bound, start first);
// blocks [NBIN, NBIN+G1T) do hs_bf16 = bf16(x @ W1): 64-row tile, 4x4 per
// thread. W1 and the 64x64 x-tile staged in LDS (coalesced float4 loads),
// inner loop pure ds_read + FMA.
// ---------------------------------------------------------------------------
__launch_bounds__(256, 4)
__global__ void gemm1_binning_kernel(const float* __restrict__ x, const float* __restrict__ W1,
                                     unsigned short* __restrict__ hsb,
                                     const int* __restrict__ ei, int E,
                                     const int* __restrict__ gbase, unsigned* __restrict__ ebuf,
                                     int N, int NBIN) {
    __shared__ float smem[FIN * FH + 64 * XSTR];   // 33.8 KB: Ws + Xs | lh (4 KB)
    int tid = threadIdx.x;
    if ((int)blockIdx.x < NBIN) {
        binning_body(ei, E, (int)blockIdx.x, gbase, ebuf, (int*)smem);
        return;
    }
    // ---- GEMM phase ----
    float* Ws = smem;                  // [64][64] row-major (k, col)
    float* Xs = smem + FIN * FH;       // [64][XSTR] row-major (row, k), padded
    int rowBase = ((int)blockIdx.x - NBIN) * 64;
    {
        const float4* W14 = (const float4*)W1;
        float4* Ws4 = (float4*)Ws;
        #pragma unroll
        for (int i = tid; i < 1024; i += 256) Ws4[i] = W14[i];
        const float4* x4 = (const float4*)x;
        #pragma unroll
        for (int i = tid; i < 1024; i += 256) {
            int row = i >> 4, kq = i & 15;
            int gr = min(rowBase + row, N - 1);    // clamp: loads never fault
            *(float4*)&Xs[row * XSTR + kq * 4] = x4[(size_t)gr * 16 + kq];
        }
    }
    __syncthreads();
    int cg = tid & 15;                 // col group: cols cg*4..+3
    int rg = tid >> 4;                 // row group: rows rg*4..+3
    int r0 = rowBase + rg * 4;
    float4 acc0 = {0,0,0,0}, acc1 = {0,0,0,0}, acc2 = {0,0,0,0}, acc3 = {0,0,0,0};
    #pragma unroll 2
    for (int kc = 0; kc < 16; ++kc) {
        float4 xa0 = *(const float4*)&Xs[(rg * 4 + 0) * XSTR + kc * 4];
        float4 xa1 = *(const float4*)&Xs[(rg * 4 + 1) * XSTR + kc * 4];
        float4 xa2 = *(const float4*)&Xs[(rg * 4 + 2) * XSTR + kc * 4];
        float4 xa3 = *(const float4*)&Xs[(rg * 4 + 3) * XSTR + kc * 4];
        const float* xa0f = (const float*)&xa0;
        const float* xa1f = (const float*)&xa1;
        const float* xa2f = (const float*)&xa2;
        const float* xa3f = (const float*)&xa3;
        #pragma unroll
        for (int j = 0; j < 4; ++j) {
            float4 wv = *(const float4*)&Ws[(kc * 4 + j) * FH + cg * 4];
            float v0 = xa0f[j], v1 = xa1f[j], v2 = xa2f[j], v3 = xa3f[j];
            acc0.x = fmaf(v0, wv.x, acc0.x); acc0.y = fmaf(v0, wv.y, acc0.y);
            acc0.z = fmaf(v0, wv.z, acc0.z); acc0.w = fmaf(v0, wv.w, acc0.w);
            acc1.x = fmaf(v1, wv.x, acc1.x); acc1.y = fmaf(v1, wv.y, acc1.y);
            acc1.z = fmaf(v1, wv.z, acc1.z); acc1.w = fmaf(v1, wv.w, acc1.w);
            acc2.x = fmaf(v2, wv.x, acc2.x); acc2.y = fmaf(v2, wv.y, acc2.y);
            acc2.z = fmaf(v2, wv.z, acc2.z); acc2.w = fmaf(v2, wv.w, acc2.w);
            acc3.x = fmaf(v3, wv.x, acc3.x); acc3.y = fmaf(v3, wv.y, acc3.y);
            acc3.z = fmaf(v3, wv.z, acc3.z); acc3.w = fmaf(v3, wv.w, acc3.w);
        }
    }
    ushort4* hsb4 = (ushort4*)hsb;
    if (r0 + 0 < N) hsb4[(size_t)(r0 + 0) * 16 + cg] =
        make_ushort4(f2bf(acc0.x), f2bf(acc0.y), f2bf(acc0.z), f2bf(acc0.w));
    if (r0 + 1 < N) hsb4[(size_t)(r0 + 1) * 16 + cg] =
        make_ushort4(f2bf(acc1.x), f2bf(acc1.y), f2bf(acc1.z), f2bf(acc1.w));
    if (r0 + 2 < N) hsb4[(size_t)(r0 + 2) * 16 + cg] =
        make_ushort4(f2bf(acc2.x), f2bf(acc2.y), f2bf(acc2.z), f2bf(acc2.w));
    if (r0 + 3 < N) hsb4[(size_t)(r0 + 3) * 16 + cg] =
        make_ushort4(f2bf(acc3.x), f2bf(acc3.y), f2bf(acc3.z), f2bf(acc3.w));
}

// ---------------------------------------------------------------------------
// Kernel: per-bucket CSR build + dinv + offs. One block per bucket; 8-deep
// batched passes; all csr stores land in the block's own contiguous region.
// ---------------------------------------------------------------------------
__launch_bounds__(256)
__global__ void bucket_csr_kernel(const unsigned* __restrict__ ebuf,
                                  const int* __restrict__ bbase,
                                  int* __restrict__ csr, int* __restrict__ offs,
                                  float* __restrict__ dinv, int N) {
    __shared__ int cnt[BW], sc[BW], cur[BW];
    int t = threadIdx.x;
    int b = blockIdx.x;
    if (t < BW) cnt[t] = 0;
    __syncthreads();
    int beg = bbase[b], end = bbase[b + 1];
    for (int i0 = beg + t; i0 < end; i0 += 2048) {
        unsigned ww[8];
        #pragma unroll
        for (int q = 0; q < 8; ++q) {
            int i = i0 + q * 256;
            ww[q] = (i < end) ? ebuf[i] : 0xFFFFFFFFu;   // valid entries < 2^24
        }
        #pragma unroll
        for (int q = 0; q < 8; ++q)
            if (ww[q] != 0xFFFFFFFFu) atomicAdd(&cnt[ww[q] >> 17], 1);
    }
    __syncthreads();
    if (t < BW) sc[t] = cnt[t];
    __syncthreads();
    for (int d = 1; d < BW; d <<= 1) {
        int u = (t < BW && t >= d) ? sc[t - d] : 0;
        __syncthreads();
        if (t < BW) sc[t] += u;
        __syncthreads();
    }
    int nodeBase = b << BSH;
    if (t < BW) {
        int node = nodeBase + t;
        int ex = beg + sc[t] - cnt[t];
        cur[t] = ex;
        if (node < N) {
            offs[node] = ex;
            dinv[node] = rsqrtf((float)(cnt[t] + 1));
        }
    }
    __syncthreads();
    for (int i0 = beg + t; i0 < end; i0 += 2048) {
        unsigned ww[8];
        #pragma unroll
        for (int q = 0; q < 8; ++q) {
            int i = i0 + q * 256;
            ww[q] = (i < end) ? ebuf[i] : 0xFFFFFFFFu;
        }
        #pragma unroll
        for (int q = 0; q < 8; ++q) {
            if (ww[q] != 0xFFFFFFFFu) {
                int pos = atomicAdd(&cur[ww[q] >> 17], 1);
                csr[pos] = (int)(ww[q] & 0x1FFFF);
            }
        }
    }
}

// ---------------------------------------------------------------------------
// Kernel: layer-1 PULL aggregation (bf16 gathers, 16 in flight, per-src dinv
// scale in-reg) fused with finalize1 + GEMM2; writes hs2 pre-scaled as bf16.
// 16 nodes/block; 16 lanes per node, lane owns one ushort4 chunk (4 feats).
// 16-deep MLP: the round-2 8-deep version ran at only 1.9 TB/s effective on
// its 86 MB random-gather set (HBM 25%) -> more outstanding requests.
// ---------------------------------------------------------------------------
__launch_bounds__(256)
__global__ void agg1_gemm2_kernel(const unsigned short* __restrict__ hsb,
                                  const int* __restrict__ csr,
                                  const int* __restrict__ offs, const float* __restrict__ dinv,
                                  const float* __restrict__ b1, const float* __restrict__ W2,
                                  unsigned short* __restrict__ hs2b, int N) {
    __shared__ float W2s[FH * FO];       // 4 KB
    __shared__ float h1s[16][68];        // 68-float row stride (16B-aligned, non-pow2)
    const ushort4* hs4 = (const ushort4*)hsb;   // 16 ushort4 per row
    int tid = threadIdx.x;
    for (int i = tid; i < FH * FO; i += 256) W2s[i] = W2[i];
    int g = tid >> 4, l = tid & 15;
    int n = blockIdx.x * 16 + g;
    if (n < N) {
        float di_n = dinv[n];
        float4 self = bf4_to_f4(hs4[(size_t)n * 16 + l]);
        float4 acc;
        acc.x = self.x * di_n; acc.y = self.y * di_n;
        acc.z = self.z * di_n; acc.w = self.w * di_n;
        int j = offs[n], end = offs[n + 1];
        for (; j + 15 < end; j += 16) {            // 16 gathers in flight
            int sI[16];
            #pragma unroll
            for (int q = 0; q < 16; ++q) sI[q] = csr[j + q];
            float dI[16];
            #pragma unroll
            for (int q = 0; q < 16; ++q) dI[q] = dinv[sI[q]];
            float4 aI[16];
            #pragma unroll
            for (int q = 0; q < 16; ++q) aI[q] = bf4_to_f4(hs4[(size_t)sI[q] * 16 + l]);
            float4 p0 = {0,0,0,0}, p1 = {0,0,0,0};
            #pragma unroll
            for (int q = 0; q < 16; q += 2) {
                p0.x = fmaf(aI[q].x, dI[q], p0.x);
                p0.y = fmaf(aI[q].y, dI[q], p0.y);
                p0.z = fmaf(aI[q].z, dI[q], p0.z);
                p0.w = fmaf(aI[q].w, dI[q], p0.w);
                p1.x = fmaf(aI[q+1].x, dI[q+1], p1.x);
                p1.y = fmaf(aI[q+1].y, dI[q+1], p1.y);
                p1.z = fmaf(aI[q+1].z, dI[q+1], p1.z);
                p1.w = fmaf(aI[q+1].w, dI[q+1], p1.w);
            }
            acc.x += p0.x + p1.x; acc.y += p0.y + p1.y;
            acc.z += p0.z + p1.z; acc.w += p0.w + p1.w;
        }
        for (; j + 7 < end; j += 8) {              // 8 in flight
            int s0 = csr[j],     s1 = csr[j + 1], s2 = csr[j + 2], s3 = csr[j + 3];
            int s4 = csr[j + 4], s5 = csr[j + 5], s6 = csr[j + 6], s7 = csr[j + 7];
            float d0 = dinv[s0], d1 = dinv[s1], d2 = dinv[s2], d3 = dinv[s3];
            float d4 = dinv[s4], d5 = dinv[s5], d6 = dinv[s6], d7 = dinv[s7];
            float4 a0 = bf4_to_f4(hs4[(size_t)s0 * 16 + l]);
            float4 a1 = bf4_to_f4(hs4[(size_t)s1 * 16 + l]);
            float4 a2 = bf4_to_f4(hs4[(size_t)s2 * 16 + l]);
            float4 a3 = bf4_to_f4(hs4[(size_t)s3 * 16 + l]);
            float4 a4 = bf4_to_f4(hs4[(size_t)s4 * 16 + l]);
            float4 a5 = bf4_to_f4(hs4[(size_t)s5 * 16 + l]);
            float4 a6 = bf4_to_f4(hs4[(size_t)s6 * 16 + l]);
            float4 a7 = bf4_to_f4(hs4[(size_t)s7 * 16 + l]);
            acc.x += (fmaf(a0.x, d0, a1.x * d1) + fmaf(a2.x, d2, a3.x * d3))
                   + (fmaf(a4.x, d4, a5.x * d5) + fmaf(a6.x, d6, a7.x * d7));
            acc.y += (fmaf(a0.y, d0, a1.y * d1) + fmaf(a2.y, d2, a3.y * d3))
                   + (fmaf(a4.y, d4, a5.y * d5) + fmaf(a6.y, d6, a7.y * d7));
            acc.z += (fmaf(a0.z, d0, a1.z * d1) + fmaf(a2.z, d2, a3.z * d3))
                   + (fmaf(a4.z, d4, a5.z * d5) + fmaf(a6.z, d6, a7.z * d7));
            acc.w += (fmaf(a0.w, d0, a1.w * d1) + fmaf(a2.w, d2, a3.w * d3))
                   + (fmaf(a4.w, d4, a5.w * d5) + fmaf(a6.w, d6, a7.w * d7));
        }
        for (; j + 1 < end; j += 2) {
            int s0 = csr[j], s1 = csr[j + 1];
            float d0 = dinv[s0], d1 = dinv[s1];
            float4 a0 = bf4_to_f4(hs4[(size_t)s0 * 16 + l]);
            float4 a1 = bf4_to_f4(hs4[(size_t)s1 * 16 + l]);
            acc.x += fmaf(a0.x, d0, a1.x * d1);
            acc.y += fmaf(a0.y, d0, a1.y * d1);
            acc.z += fmaf(a0.z, d0, a1.z * d1);
            acc.w += fmaf(a0.w, d0, a1.w * d1);
        }
        if (j < end) {
            int s0 = csr[j];
            float d0 = dinv[s0];
            float4 a0 = bf4_to_f4(hs4[(size_t)s0 * 16 + l]);
            acc.x = fmaf(a0.x, d0, acc.x); acc.y = fmaf(a0.y, d0, acc.y);
            acc.z = fmaf(a0.z, d0, acc.z); acc.w = fmaf(a0.w, d0, acc.w);
        }
        float4 bb = ((const float4*)b1)[l];
        float4 h;
        h.x = fmaxf(fmaf(di_n, acc.x, bb.x), 0.f);
        h.y = fmaxf(fmaf(di_n, acc.y, bb.y), 0.f);
        h.z = fmaxf(fmaf(di_n, acc.z, bb.z), 0.f);
        h.w = fmaxf(fmaf(di_n, acc.w, bb.w), 0.f);
        *((float4*)&h1s[g][l * 4]) = h;
    }
    __syncthreads();
    int r = tid >> 4, o = tid & 15;     // 16 rows x 16 out-cols
    int n2 = blockIdx.x * 16 + r;
    if (n2 < N) {
        float acc = 0.f;
        #pragma unroll
        for (int jj = 0; jj < FH; ++jj)
            acc = fmaf(h1s[r][jj], W2s[jj * FO + o], acc);
        hs2b[(size_t)n2 * FO + o] = f2bf(acc * dinv[n2]);   // pre-scaled bf16
    }
}

// ---------------------------------------------------------------------------
// Kernel: layer-2 PULL aggregation (16 gathers in flight) + bias +
// log_softmax. hs2b table is 3.2 MB -> fits per-XCD L2; gathers 2B/lane.
// ---------------------------------------------------------------------------
__launch_bounds__(256)
__global__ void agg2_softmax_kernel(const unsigned short* __restrict__ hs2b,
                                    const int* __restrict__ csr,
                                    const int* __restrict__ offs, const float* __restrict__ dinv,
                                    const float* __restrict__ b2, float* __restrict__ out, int N) {
    int tid = threadIdx.x;
    int g = tid >> 4, o = tid & 15;
    int n = blockIdx.x * 16 + g;
    float v = 0.f;
    if (n < N) {
        float acc = bf2f(hs2b[(size_t)n * 16 + o]);    // self loop (pre-scaled)
        int j = offs[n], end = offs[n + 1];
        for (; j + 15 < end; j += 16) {
            int sI[16];
            #pragma unroll
            for (int q = 0; q < 16; ++q) sI[q] = csr[j + q];
            unsigned short hI[16];
            #pragma unroll
            for (int q = 0; q < 16; ++q) hI[q] = hs2b[(size_t)sI[q] * 16 + o];
            float p0 = 0.f, p1 = 0.f;
            #pragma unroll
            for (int q = 0; q < 16; q += 2) {
                p0 += bf2f(hI[q]);
                p1 += bf2f(hI[q + 1]);
            }
            acc += p0 + p1;
        }
        for (; j + 7 < end; j += 8) {
            int s0 = csr[j],     s1 = csr[j + 1], s2 = csr[j + 2], s3 = csr[j + 3];
            int s4 = csr[j + 4], s5 = csr[j + 5], s6 = csr[j + 6], s7 = csr[j + 7];
            float t0 = bf2f(hs2b[(size_t)s0 * 16 + o]) + bf2f(hs2b[(size_t)s1 * 16 + o]);
            float t1 = bf2f(hs2b[(size_t)s2 * 16 + o]) + bf2f(hs2b[(size_t)s3 * 16 + o]);
            float t2 = bf2f(hs2b[(size_t)s4 * 16 + o]) + bf2f(hs2b[(size_t)s5 * 16 + o]);
            float t3 = bf2f(hs2b[(size_t)s6 * 16 + o]) + bf2f(hs2b[(size_t)s7 * 16 + o]);
            acc += (t0 + t1) + (t2 + t3);
        }
        for (; j < end; ++j) acc += bf2f(hs2b[(size_t)csr[j] * 16 + o]);
        v = fmaf(dinv[n], acc, b2[o]);
    }
    float m = v;
    #pragma unroll
    for (int s = 8; s >= 1; s >>= 1) m = fmaxf(m, __shfl_xor(m, s, 64));
    float ex = __expf(v - m);
    float sum = ex;
    #pragma unroll
    for (int s = 8; s >= 1; s >>= 1) sum += __shfl_xor(sum, s, 64);
    if (n < N) out[(size_t)n * FO + o] = v - m - __logf(sum);
}

// ---------------------------------------------------------------------------
extern "C" void kernel_launch(void* const* d_in, const int* in_sizes, int n_in,
                              void* d_out, int out_size, void* d_ws, size_t ws_size,
                              hipStream_t stream) {
    const float* x  = (const float*)d_in[0];
    const int*   ei = (const int*)d_in[1];     // int32
    const float* W1 = (const float*)d_in[2];
    const float* b1 = (const float*)d_in[3];
    const float* W2 = (const float*)d_in[4];
    const float* b2 = (const float*)d_in[5];
    float* out = (float*)d_out;

    const int N = in_sizes[0] / FIN;
    const int E = in_sizes[1] / 2;
    const int NCH  = (E + EPB - 1) / EPB;            // hist/binning chunks
    const int NB4  = (N + BW - 1) / BW;              // buckets actually used
    const int G1T  = (N + 63) / 64;                  // gemm 64-row tiles
    const int GA   = (N + 15) / 16;                  // agg blocks

    char* ws = (char*)d_ws;
    size_t off = 0;
    auto alloc = [&](size_t bytes) -> void* {
        off = (off + 255) & ~(size_t)255;
        void* p = ws + off;
        off += bytes;
        return p;
    };
    float*          dinv   = (float*)alloc((size_t)N * 4);               //  0.4 MB
    unsigned short* hsb    = (unsigned short*)alloc((size_t)N * FH * 2); // 12.8 MB
    unsigned short* hs2b   = (unsigned short*)alloc((size_t)N * FO * 2); //  3.2 MB
    int*            offs   = (int*)alloc((size_t)(N + 1) * 4);           //  0.4 MB
    int*            bcnt   = (int*)alloc(NBUCK * 4);
    int*            bbase  = (int*)alloc((NBUCK + 1) * 4);
    unsigned short* gchist = (unsigned short*)alloc((size_t)NCH * NBUCK * 2); // 0.8 MB
    int*            gbase  = (int*)alloc((size_t)NCH * NBUCK * 4);       //  1.6 MB
    // ebuf + csr (2*E ints = 12.8 MB): in ws if it fits, else alias the x
    // input buffer (25.6 MB, dead after the gemm phase; harness restores d_in
    // before every launch; ws_size constant -> capture-stable branch).
    unsigned* ebuf;
    int*      csr;
    bool ws_fits = (ws_size >= off + 512 + (size_t)E * 8);
    if (ws_fits) {
        ebuf = (unsigned*)alloc((size_t)E * 4);
        csr  = (int*)     alloc((size_t)E * 4);
    } else {
        ebuf = (unsigned*)x;
        csr  = (int*)x + E;
    }

    hipMemsetAsync(bcnt, 0, NBUCK * 4, stream);

    hist_kernel<<<NCH, 256, 0, stream>>>(ei, E, bcnt, gchist);
    bucket_scan_kernel<<<1, NBUCK, 0, stream>>>(bcnt, bbase, gchist, gbase, NCH,
                                                offs, N, E);
    if (ws_fits) {
        // Overlap: binning blocks first, gemm blocks backfill.
        gemm1_binning_kernel<<<NCH + G1T, 256, 0, stream>>>(x, W1, hsb, ei, E,
                                                            gbase, ebuf, N, NCH);
    } else {
        // ebuf aliases x: gemm must fully precede binning.
        gemm1_binning_kernel<<<G1T, 256, 0, stream>>>(x, W1, hsb, ei, E,
                                                      gbase, ebuf, N, 0);
        binning_kernel<<<NCH, 256, 0, stream>>>(ei, E, gbase, ebuf);
    }
    bucket_csr_kernel<<<NB4, 256, 0, stream>>>(ebuf, bbase, csr, offs, dinv, N);
    agg1_gemm2_kernel<<<GA, 256, 0, stream>>>(hsb, csr, offs, dinv, b1, W2, hs2b, N);
    agg2_softmax_kernel<<<GA, 256, 0, stream>>>(hs2b, csr, offs, dinv, b2, out, N);
}

// Round 5
// 229.864 us; speedup vs baseline: 1.2740x; 1.0629x over previous
//
#include <hip/hip_runtime.h>

// Feature dims fixed by the problem
constexpr int FIN = 64;   // input features
constexpr int FH  = 64;   // hidden
constexpr int FO  = 16;   // output

// edge_index arrives as int32 (harness integer convention), flat [2][E]:
// src = ei[e], dst = ei[e + E].

// Bucket sort parameters: bucket = dst >> 7 (128 nodes per bucket).
constexpr int BSH      = 7;
constexpr int BW       = 1 << BSH;  // 128 nodes / bucket
constexpr int NBUCK    = 1024;      // covers N up to 131072
// ONE chunk size shared by hist and binning. 4096 edges/chunk -> 391 chunks:
// enough blocks that the load->atomic->store chains are hidden by TLP
// (16384 gave only 98 blocks -> <1 block/CU -> 27 us serial-chain stragglers).
constexpr int EPB      = 4096;

// GEMM x-tile LDS stride: 68 floats (pad 64+4) so the 4-row-strided compute
// reads alias only 2-way on banks (2-way is free on CDNA4).
constexpr int XSTR     = 68;

// bf16 helpers (manual RNE; exact expand)
__device__ inline unsigned short f2bf(float f) {
    unsigned u = __float_as_uint(f);
    return (unsigned short)((u + 0x7FFFu + ((u >> 16) & 1u)) >> 16);
}
__device__ inline float bf2f(unsigned short h) {
    return __uint_as_float((unsigned)h << 16);
}
__device__ inline float4 bf4_to_f4(ushort4 u) {
    float4 f;
    f.x = bf2f(u.x); f.y = bf2f(u.y); f.z = bf2f(u.z); f.w = bf2f(u.w);
    return f;
}

// ---------------------------------------------------------------------------
// Kernel: dst-bucket histogram. One block per 4K-edge chunk; 8-deep batched
// loads (independent) then 8 LDS-atomic chains. Stores ONLY the per-chunk
// hist (gchist, ushort). Bucket totals are derived from gchist by the scan
// kernel -> no bcnt array, no memset, no global atomics here.
// ---------------------------------------------------------------------------
__launch_bounds__(256)
__global__ void hist_kernel(const int* __restrict__ ei, int E,
                            unsigned short* __restrict__ gchist) {
    __shared__ int lh[NBUCK];
    int t = threadIdx.x;
    for (int i = t; i < NBUCK; i += 256) lh[i] = 0;
    __syncthreads();
    int base = blockIdx.x * EPB;
    int lim  = min(E, base + EPB);
    for (int e0 = base + t; e0 < lim; e0 += 2048) {
        int dd[8];
        #pragma unroll
        for (int q = 0; q < 8; ++q) {
            int e = e0 + q * 256;
            dd[q] = (e < lim) ? ei[E + e] : -1;
        }
        #pragma unroll
        for (int q = 0; q < 8; ++q)
            if (dd[q] >= 0) atomicAdd(&lh[dd[q] >> BSH], 1);
    }
    __syncthreads();
    unsigned short* gh = gchist + (size_t)blockIdx.x * NBUCK;
    for (int b = t; b < NBUCK; b += 256)
        gh[b] = (unsigned short)lh[b];              // c <= EPB=4096, fits ushort
}

// ---------------------------------------------------------------------------
// Kernel: bucket totals from gchist (pass 1), exclusive scan -> bbase,
// then per-(chunk,bucket) deterministic write bases (pass 2):
// gbase[c][t] = bbase[t] + sum_{c'<c} gchist[c'][t].
// Single block of 1024 threads, thread t owns bucket t. Also offs[N] = E.
// ---------------------------------------------------------------------------
__launch_bounds__(1024)
__global__ void bucket_scan_kernel(const unsigned short* __restrict__ gchist,
                                   int* __restrict__ bbase, int* __restrict__ gbase,
                                   int NCH, int* __restrict__ offs, int N, int E) {
    __shared__ int s[NBUCK];
    int t = threadIdx.x;
    int v = 0;
    #pragma unroll 8
    for (int c = 0; c < NCH; ++c)
        v += (int)gchist[(size_t)c * NBUCK + t];
    s[t] = v;
    __syncthreads();
    for (int d = 1; d < NBUCK; d <<= 1) {
        int u = (t >= d) ? s[t - d] : 0;
        __syncthreads();
        s[t] += u;
        __syncthreads();
    }
    int ex = s[t] - v;
    bbase[t] = ex;
    if (t == NBUCK - 1) {
        bbase[NBUCK] = s[t];   // == E
        offs[N] = E;
    }
    // per-chunk bases: coalesced along t; loads independent -> deep unroll
    int run = ex;
    #pragma unroll 8
    for (int c = 0; c < NCH; ++c) {
        gbase[(size_t)c * NBUCK + t] = run;
        run += (int)gchist[(size_t)c * NBUCK + t];
    }
}

// ---------------------------------------------------------------------------
// Binning device body: cursor row comes precomputed from gbase -> single
// pass, LDS atomics only. 8-deep batched: 8 independent (d,src) loads, then
// 8 atomic+store chains overlapped. EPB=4096 -> exactly 2 batches/thread.
// Packed word: src | (dst & 127) << 17 (N < 2^17).
// ---------------------------------------------------------------------------
__device__ inline void binning_body(const int* __restrict__ ei, int E, int chunk,
                                    const int* __restrict__ gbase,
                                    unsigned* __restrict__ ebuf, int* lh) {
    int t = threadIdx.x;
    const int* gb = gbase + (size_t)chunk * NBUCK;
    for (int i = t; i < NBUCK; i += 256) lh[i] = gb[i];
    __syncthreads();
    int base = chunk * EPB;
    int lim  = min(E, base + EPB);
    for (int e0 = base + t; e0 < lim; e0 += 2048) {
        int dd[8], ss[8];
        #pragma unroll
        for (int q = 0; q < 8; ++q) {
            int e = e0 + q * 256;
            if (e < lim) { dd[q] = ei[E + e]; ss[q] = ei[e]; } else dd[q] = -1;
        }
        #pragma unroll
        for (int q = 0; q < 8; ++q) {
            if (dd[q] >= 0) {
                int pos = atomicAdd(&lh[dd[q] >> BSH], 1);
                ebuf[pos] = (unsigned)ss[q] | ((unsigned)(dd[q] & (BW - 1)) << 17);
            }
        }
    }
}

__launch_bounds__(256)
__global__ void binning_kernel(const int* __restrict__ ei, int E,
                               const int* __restrict__ gbase, unsigned* __restrict__ ebuf) {
    __shared__ int lh[NBUCK];
    binning_body(ei, E, blockIdx.x, gbase, ebuf, lh);
}

// ---------------------------------------------------------------------------
// Fused kernel: blocks [0, NBIN) do binning (latency-bound, start first);
// blocks [NBIN, NBIN+G1T) do hs_bf16 = bf16(x @ W1): 64-row tile, 4x4 per
// thread. W1 and the 64x64 x-tile staged in LDS (coalesced float4 loads),
// inner loop pure ds_read + FMA.
// ---------------------------------------------------------------------------
__launch_bounds__(256, 4)
__global__ void gemm1_binning_kernel(const float* __restrict__ x, const float* __restrict__ W1,
                                     unsigned short* __restrict__ hsb,
                                     const int* __restrict__ ei, int E,
                                     const int* __restrict__ gbase, unsigned* __restrict__ ebuf,
                                     int N, int NBIN) {
    __shared__ float smem[FIN * FH + 64 * XSTR];   // 33.8 KB: Ws + Xs | lh (4 KB)
    int tid = threadIdx.x;
    if ((int)blockIdx.x < NBIN) {
        binning_body(ei, E, (int)blockIdx.x, gbase, ebuf, (int*)smem);
        return;
    }
    // ---- GEMM phase ----
    float* Ws = smem;                  // [64][64] row-major (k, col)
    float* Xs = smem + FIN * FH;       // [64][XSTR] row-major (row, k), padded
    int rowBase = ((int)blockIdx.x - NBIN) * 64;
    {
        const float4* W14 = (const float4*)W1;
        float4* Ws4 = (float4*)Ws;
        #pragma unroll
        for (int i = tid; i < 1024; i += 256) Ws4[i] = W14[i];
        const float4* x4 = (const float4*)x;
        #pragma unroll
        for (int i = tid; i < 1024; i += 256) {
            int row = i >> 4, kq = i & 15;
            int gr = min(rowBase + row, N - 1);    // clamp: loads never fault
            *(float4*)&Xs[row * XSTR + kq * 4] = x4[(size_t)gr * 16 + kq];
        }
    }
    __syncthreads();
    int cg = tid & 15;                 // col group: cols cg*4..+3
    int rg = tid >> 4;                 // row group: rows rg*4..+3
    int r0 = rowBase + rg * 4;
    float4 acc0 = {0,0,0,0}, acc1 = {0,0,0,0}, acc2 = {0,0,0,0}, acc3 = {0,0,0,0};
    #pragma unroll 2
    for (int kc = 0; kc < 16; ++kc) {
        float4 xa0 = *(const float4*)&Xs[(rg * 4 + 0) * XSTR + kc * 4];
        float4 xa1 = *(const float4*)&Xs[(rg * 4 + 1) * XSTR + kc * 4];
        float4 xa2 = *(const float4*)&Xs[(rg * 4 + 2) * XSTR + kc * 4];
        float4 xa3 = *(const float4*)&Xs[(rg * 4 + 3) * XSTR + kc * 4];
        const float* xa0f = (const float*)&xa0;
        const float* xa1f = (const float*)&xa1;
        const float* xa2f = (const float*)&xa2;
        const float* xa3f = (const float*)&xa3;
        #pragma unroll
        for (int j = 0; j < 4; ++j) {
            float4 wv = *(const float4*)&Ws[(kc * 4 + j) * FH + cg * 4];
            float v0 = xa0f[j], v1 = xa1f[j], v2 = xa2f[j], v3 = xa3f[j];
            acc0.x = fmaf(v0, wv.x, acc0.x); acc0.y = fmaf(v0, wv.y, acc0.y);
            acc0.z = fmaf(v0, wv.z, acc0.z); acc0.w = fmaf(v0, wv.w, acc0.w);
            acc1.x = fmaf(v1, wv.x, acc1.x); acc1.y = fmaf(v1, wv.y, acc1.y);
            acc1.z = fmaf(v1, wv.z, acc1.z); acc1.w = fmaf(v1, wv.w, acc1.w);
            acc2.x = fmaf(v2, wv.x, acc2.x); acc2.y = fmaf(v2, wv.y, acc2.y);
            acc2.z = fmaf(v2, wv.z, acc2.z); acc2.w = fmaf(v2, wv.w, acc2.w);
            acc3.x = fmaf(v3, wv.x, acc3.x); acc3.y = fmaf(v3, wv.y, acc3.y);
            acc3.z = fmaf(v3, wv.z, acc3.z); acc3.w = fmaf(v3, wv.w, acc3.w);
        }
    }
    ushort4* hsb4 = (ushort4*)hsb;
    if (r0 + 0 < N) hsb4[(size_t)(r0 + 0) * 16 + cg] =
        make_ushort4(f2bf(acc0.x), f2bf(acc0.y), f2bf(acc0.z), f2bf(acc0.w));
    if (r0 + 1 < N) hsb4[(size_t)(r0 + 1) * 16 + cg] =
        make_ushort4(f2bf(acc1.x), f2bf(acc1.y), f2bf(acc1.z), f2bf(acc1.w));
    if (r0 + 2 < N) hsb4[(size_t)(r0 + 2) * 16 + cg] =
        make_ushort4(f2bf(acc2.x), f2bf(acc2.y), f2bf(acc2.z), f2bf(acc2.w));
    if (r0 + 3 < N) hsb4[(size_t)(r0 + 3) * 16 + cg] =
        make_ushort4(f2bf(acc3.x), f2bf(acc3.y), f2bf(acc3.z), f2bf(acc3.w));
}

// ---------------------------------------------------------------------------
// Kernel: per-bucket CSR build + dinv + offs. One block per bucket; 8-deep
// batched passes; all csr stores land in the block's own contiguous region.
// ---------------------------------------------------------------------------
__launch_bounds__(256)
__global__ void bucket_csr_kernel(const unsigned* __restrict__ ebuf,
                                  const int* __restrict__ bbase,
                                  int* __restrict__ csr, int* __restrict__ offs,
                                  float* __restrict__ dinv, int N) {
    __shared__ int cnt[BW], sc[BW], cur[BW];
    int t = threadIdx.x;
    int b = blockIdx.x;
    if (t < BW) cnt[t] = 0;
    __syncthreads();
    int beg = bbase[b], end = bbase[b + 1];
    for (int i0 = beg + t; i0 < end; i0 += 2048) {
        unsigned ww[8];
        #pragma unroll
        for (int q = 0; q < 8; ++q) {
            int i = i0 + q * 256;
            ww[q] = (i < end) ? ebuf[i] : 0xFFFFFFFFu;   // valid entries < 2^24
        }
        #pragma unroll
        for (int q = 0; q < 8; ++q)
            if (ww[q] != 0xFFFFFFFFu) atomicAdd(&cnt[ww[q] >> 17], 1);
    }
    __syncthreads();
    if (t < BW) sc[t] = cnt[t];
    __syncthreads();
    for (int d = 1; d < BW; d <<= 1) {
        int u = (t < BW && t >= d) ? sc[t - d] : 0;
        __syncthreads();
        if (t < BW) sc[t] += u;
        __syncthreads();
    }
    int nodeBase = b << BSH;
    if (t < BW) {
        int node = nodeBase + t;
        int ex = beg + sc[t] - cnt[t];
        cur[t] = ex;
        if (node < N) {
            offs[node] = ex;
            dinv[node] = rsqrtf((float)(cnt[t] + 1));
        }
    }
    __syncthreads();
    for (int i0 = beg + t; i0 < end; i0 += 2048) {
        unsigned ww[8];
        #pragma unroll
        for (int q = 0; q < 8; ++q) {
            int i = i0 + q * 256;
            ww[q] = (i < end) ? ebuf[i] : 0xFFFFFFFFu;
        }
        #pragma unroll
        for (int q = 0; q < 8; ++q) {
            if (ww[q] != 0xFFFFFFFFu) {
                int pos = atomicAdd(&cur[ww[q] >> 17], 1);
                csr[pos] = (int)(ww[q] & 0x1FFFF);
            }
        }
    }
}

// ---------------------------------------------------------------------------
// Kernel: layer-1 PULL aggregation (bf16 gathers, 8 in flight, per-src dinv
// scale in-reg) fused with finalize1 + GEMM2; writes hs2 pre-scaled as bf16.
// 16 nodes/block; 16 lanes per node, lane owns one ushort4 chunk (4 feats).
// 8-deep is the measured sweet spot (16-deep forced reg-serialization at
// VGPR=36 and regressed 46->56 us).
// ---------------------------------------------------------------------------
__launch_bounds__(256)
__global__ void agg1_gemm2_kernel(const unsigned short* __restrict__ hsb,
                                  const int* __restrict__ csr,
                                  const int* __restrict__ offs, const float* __restrict__ dinv,
                                  const float* __restrict__ b1, const float* __restrict__ W2,
                                  unsigned short* __restrict__ hs2b, int N) {
    __shared__ float W2s[FH * FO];       // 4 KB
    __shared__ float h1s[16][68];        // 68-float row stride (16B-aligned, non-pow2)
    const ushort4* hs4 = (const ushort4*)hsb;   // 16 ushort4 per row
    int tid = threadIdx.x;
    for (int i = tid; i < FH * FO; i += 256) W2s[i] = W2[i];
    int g = tid >> 4, l = tid & 15;
    int n = blockIdx.x * 16 + g;
    if (n < N) {
        float di_n = dinv[n];
        float4 self = bf4_to_f4(hs4[(size_t)n * 16 + l]);
        float4 acc;
        acc.x = self.x * di_n; acc.y = self.y * di_n;
        acc.z = self.z * di_n; acc.w = self.w * di_n;
        int j = offs[n], end = offs[n + 1];
        for (; j + 7 < end; j += 8) {              // 8 gathers in flight
            int s0 = csr[j],     s1 = csr[j + 1], s2 = csr[j + 2], s3 = csr[j + 3];
            int s4 = csr[j + 4], s5 = csr[j + 5], s6 = csr[j + 6], s7 = csr[j + 7];
            float d0 = dinv[s0], d1 = dinv[s1], d2 = dinv[s2], d3 = dinv[s3];
            float d4 = dinv[s4], d5 = dinv[s5], d6 = dinv[s6], d7 = dinv[s7];
            float4 a0 = bf4_to_f4(hs4[(size_t)s0 * 16 + l]);
            float4 a1 = bf4_to_f4(hs4[(size_t)s1 * 16 + l]);
            float4 a2 = bf4_to_f4(hs4[(size_t)s2 * 16 + l]);
            float4 a3 = bf4_to_f4(hs4[(size_t)s3 * 16 + l]);
            float4 a4 = bf4_to_f4(hs4[(size_t)s4 * 16 + l]);
            float4 a5 = bf4_to_f4(hs4[(size_t)s5 * 16 + l]);
            float4 a6 = bf4_to_f4(hs4[(size_t)s6 * 16 + l]);
            float4 a7 = bf4_to_f4(hs4[(size_t)s7 * 16 + l]);
            acc.x += (fmaf(a0.x, d0, a1.x * d1) + fmaf(a2.x, d2, a3.x * d3))
                   + (fmaf(a4.x, d4, a5.x * d5) + fmaf(a6.x, d6, a7.x * d7));
            acc.y += (fmaf(a0.y, d0, a1.y * d1) + fmaf(a2.y, d2, a3.y * d3))
                   + (fmaf(a4.y, d4, a5.y * d5) + fmaf(a6.y, d6, a7.y * d7));
            acc.z += (fmaf(a0.z, d0, a1.z * d1) + fmaf(a2.z, d2, a3.z * d3))
                   + (fmaf(a4.z, d4, a5.z * d5) + fmaf(a6.z, d6, a7.z * d7));
            acc.w += (fmaf(a0.w, d0, a1.w * d1) + fmaf(a2.w, d2, a3.w * d3))
                   + (fmaf(a4.w, d4, a5.w * d5) + fmaf(a6.w, d6, a7.w * d7));
        }
        for (; j + 1 < end; j += 2) {
            int s0 = csr[j], s1 = csr[j + 1];
            float d0 = dinv[s0], d1 = dinv[s1];
            float4 a0 = bf4_to_f4(hs4[(size_t)s0 * 16 + l]);
            float4 a1 = bf4_to_f4(hs4[(size_t)s1 * 16 + l]);
            acc.x += fmaf(a0.x, d0, a1.x * d1);
            acc.y += fmaf(a0.y, d0, a1.y * d1);
            acc.z += fmaf(a0.z, d0, a1.z * d1);
            acc.w += fmaf(a0.w, d0, a1.w * d1);
        }
        if (j < end) {
            int s0 = csr[j];
            float d0 = dinv[s0];
            float4 a0 = bf4_to_f4(hs4[(size_t)s0 * 16 + l]);
            acc.x = fmaf(a0.x, d0, acc.x); acc.y = fmaf(a0.y, d0, acc.y);
            acc.z = fmaf(a0.z, d0, acc.z); acc.w = fmaf(a0.w, d0, acc.w);
        }
        float4 bb = ((const float4*)b1)[l];
        float4 h;
        h.x = fmaxf(fmaf(di_n, acc.x, bb.x), 0.f);
        h.y = fmaxf(fmaf(di_n, acc.y, bb.y), 0.f);
        h.z = fmaxf(fmaf(di_n, acc.z, bb.z), 0.f);
        h.w = fmaxf(fmaf(di_n, acc.w, bb.w), 0.f);
        *((float4*)&h1s[g][l * 4]) = h;
    }
    __syncthreads();
    int r = tid >> 4, o = tid & 15;     // 16 rows x 16 out-cols
    int n2 = blockIdx.x * 16 + r;
    if (n2 < N) {
        float acc = 0.f;
        #pragma unroll
        for (int jj = 0; jj < FH; ++jj)
            acc = fmaf(h1s[r][jj], W2s[jj * FO + o], acc);
        hs2b[(size_t)n2 * FO + o] = f2bf(acc * dinv[n2]);   // pre-scaled bf16
    }
}

// ---------------------------------------------------------------------------
// Kernel: layer-2 PULL aggregation (8 gathers in flight) + bias + log_softmax.
// hs2b table is 3.2 MB -> fits per-XCD L2; gathers are 2B/lane.
// ---------------------------------------------------------------------------
__launch_bounds__(256)
__global__ void agg2_softmax_kernel(const unsigned short* __restrict__ hs2b,
                                    const int* __restrict__ csr,
                                    const int* __restrict__ offs, const float* __restrict__ dinv,
                                    const float* __restrict__ b2, float* __restrict__ out, int N) {
    int tid = threadIdx.x;
    int g = tid >> 4, o = tid & 15;
    int n = blockIdx.x * 16 + g;
    float v = 0.f;
    if (n < N) {
        float acc = bf2f(hs2b[(size_t)n * 16 + o]);    // self loop (pre-scaled)
        int j = offs[n], end = offs[n + 1];
        for (; j + 7 < end; j += 8) {
            int s0 = csr[j],     s1 = csr[j + 1], s2 = csr[j + 2], s3 = csr[j + 3];
            int s4 = csr[j + 4], s5 = csr[j + 5], s6 = csr[j + 6], s7 = csr[j + 7];
            float t0 = bf2f(hs2b[(size_t)s0 * 16 + o]) + bf2f(hs2b[(size_t)s1 * 16 + o]);
            float t1 = bf2f(hs2b[(size_t)s2 * 16 + o]) + bf2f(hs2b[(size_t)s3 * 16 + o]);
            float t2 = bf2f(hs2b[(size_t)s4 * 16 + o]) + bf2f(hs2b[(size_t)s5 * 16 + o]);
            float t3 = bf2f(hs2b[(size_t)s6 * 16 + o]) + bf2f(hs2b[(size_t)s7 * 16 + o]);
            acc += (t0 + t1) + (t2 + t3);
        }
        for (; j < end; ++j) acc += bf2f(hs2b[(size_t)csr[j] * 16 + o]);
        v = fmaf(dinv[n], acc, b2[o]);
    }
    float m = v;
    #pragma unroll
    for (int s = 8; s >= 1; s >>= 1) m = fmaxf(m, __shfl_xor(m, s, 64));
    float ex = __expf(v - m);
    float sum = ex;
    #pragma unroll
    for (int s = 8; s >= 1; s >>= 1) sum += __shfl_xor(sum, s, 64);
    if (n < N) out[(size_t)n * FO + o] = v - m - __logf(sum);
}

// ---------------------------------------------------------------------------
extern "C" void kernel_launch(void* const* d_in, const int* in_sizes, int n_in,
                              void* d_out, int out_size, void* d_ws, size_t ws_size,
                              hipStream_t stream) {
    const float* x  = (const float*)d_in[0];
    const int*   ei = (const int*)d_in[1];     // int32
    const float* W1 = (const float*)d_in[2];
    const float* b1 = (const float*)d_in[3];
    const float* W2 = (const float*)d_in[4];
    const float* b2 = (const float*)d_in[5];
    float* out = (float*)d_out;

    const int N = in_sizes[0] / FIN;
    const int E = in_sizes[1] / 2;
    const int NCH  = (E + EPB - 1) / EPB;            // hist/binning chunks
    const int NB4  = (N + BW - 1) / BW;              // buckets actually used
    const int G1T  = (N + 63) / 64;                  // gemm 64-row tiles
    const int GA   = (N + 15) / 16;                  // agg blocks

    char* ws = (char*)d_ws;
    size_t off = 0;
    auto alloc = [&](size_t bytes) -> void* {
        off = (off + 255) & ~(size_t)255;
        void* p = ws + off;
        off += bytes;
        return p;
    };
    float*          dinv   = (float*)alloc((size_t)N * 4);               //  0.4 MB
    unsigned short* hsb    = (unsigned short*)alloc((size_t)N * FH * 2); // 12.8 MB
    unsigned short* hs2b   = (unsigned short*)alloc((size_t)N * FO * 2); //  3.2 MB
    int*            offs   = (int*)alloc((size_t)(N + 1) * 4);           //  0.4 MB
    int*            bbase  = (int*)alloc((NBUCK + 1) * 4);
    unsigned short* gchist = (unsigned short*)alloc((size_t)NCH * NBUCK * 2); // 0.8 MB
    int*            gbase  = (int*)alloc((size_t)NCH * NBUCK * 4);       //  1.6 MB
    // ebuf + csr (2*E ints = 12.8 MB): in ws if it fits, else alias the x
    // input buffer (25.6 MB, dead after the gemm phase; harness restores d_in
    // before every launch; ws_size constant -> capture-stable branch).
    unsigned* ebuf;
    int*      csr;
    bool ws_fits = (ws_size >= off + 512 + (size_t)E * 8);
    if (ws_fits) {
        ebuf = (unsigned*)alloc((size_t)E * 4);
        csr  = (int*)     alloc((size_t)E * 4);
    } else {
        ebuf = (unsigned*)x;
        csr  = (int*)x + E;
    }

    hist_kernel<<<NCH, 256, 0, stream>>>(ei, E, gchist);
    bucket_scan_kernel<<<1, NBUCK, 0, stream>>>(gchist, bbase, gbase, NCH,
                                                offs, N, E);
    if (ws_fits) {
        // Overlap: binning blocks first, gemm blocks backfill.
        gemm1_binning_kernel<<<NCH + G1T, 256, 0, stream>>>(x, W1, hsb, ei, E,
                                                            gbase, ebuf, N, NCH);
    } else {
        // ebuf aliases x: gemm must fully precede binning.
        gemm1_binning_kernel<<<G1T, 256, 0, stream>>>(x, W1, hsb, ei, E,
                                                      gbase, ebuf, N, 0);
        binning_kernel<<<NCH, 256, 0, stream>>>(ei, E, gbase, ebuf);
    }
    bucket_csr_kernel<<<NB4, 256, 0, stream>>>(ebuf, bbase, csr, offs, dinv, N);
    agg1_gemm2_kernel<<<GA, 256, 0, stream>>>(hsb, csr, offs, dinv, b1, W2, hs2b, N);
    agg2_softmax_kernel<<<GA, 256, 0, stream>>>(hs2b, csr, offs, dinv, b2, out, N);
}

// Round 6
// 198.089 us; speedup vs baseline: 1.4783x; 1.1604x over previous
//
#include <hip/hip_runtime.h>

// Feature dims fixed by the problem
constexpr int FIN = 64;   // input features
constexpr int FH  = 64;   // hidden
constexpr int FO  = 16;   // output

// edge_index arrives as int32 (harness integer convention), flat [2][E]:
// src = ei[e], dst = ei[e + E].

// Bucket sort parameters: bucket = dst >> 7 (128 nodes per bucket).
constexpr int BSH      = 7;
constexpr int BW       = 1 << BSH;  // 128 nodes / bucket
constexpr int NBUCK    = 1024;      // covers N up to 131072
// ONE chunk size shared by hist and binning. 4096 edges/chunk -> 391 chunks:
// enough blocks that the load->atomic->store chains are hidden by TLP.
constexpr int EPB      = 4096;
// Hierarchical scan: chunks are split into NGRP groups so the serial
// single-block scan touches only NGRP values per bucket (round-5 lesson:
// a single 1024-thread block streaming 4 MB = 46 us at single-CU BW).
constexpr int NGRP     = 32;

// GEMM x-tile LDS stride: 68 floats (pad 64+4) so the 4-row-strided compute
// reads alias only 2-way on banks (2-way is free on CDNA4).
constexpr int XSTR     = 68;

// bf16 helpers (manual RNE; exact expand)
__device__ inline unsigned short f2bf(float f) {
    unsigned u = __float_as_uint(f);
    return (unsigned short)((u + 0x7FFFu + ((u >> 16) & 1u)) >> 16);
}
__device__ inline float bf2f(unsigned short h) {
    return __uint_as_float((unsigned)h << 16);
}
__device__ inline float4 bf4_to_f4(ushort4 u) {
    float4 f;
    f.x = bf2f(u.x); f.y = bf2f(u.y); f.z = bf2f(u.z); f.w = bf2f(u.w);
    return f;
}

// ---------------------------------------------------------------------------
// Kernel: dst-bucket histogram. One block per 4K-edge chunk; 8-deep batched
// loads (independent) then 8 LDS-atomic chains. Stores ONLY the per-chunk
// hist (gchist, ushort).
// ---------------------------------------------------------------------------
__launch_bounds__(256)
__global__ void hist_kernel(const int* __restrict__ ei, int E,
                            unsigned short* __restrict__ gchist) {
    __shared__ int lh[NBUCK];
    int t = threadIdx.x;
    for (int i = t; i < NBUCK; i += 256) lh[i] = 0;
    __syncthreads();
    int base = blockIdx.x * EPB;
    int lim  = min(E, base + EPB);
    for (int e0 = base + t; e0 < lim; e0 += 2048) {
        int dd[8];
        #pragma unroll
        for (int q = 0; q < 8; ++q) {
            int e = e0 + q * 256;
            dd[q] = (e < lim) ? ei[E + e] : -1;
        }
        #pragma unroll
        for (int q = 0; q < 8; ++q)
            if (dd[q] >= 0) atomicAdd(&lh[dd[q] >> BSH], 1);
    }
    __syncthreads();
    unsigned short* gh = gchist + (size_t)blockIdx.x * NBUCK;
    for (int b = t; b < NBUCK; b += 256)
        gh[b] = (unsigned short)lh[b];              // c <= EPB=4096, fits ushort
}

// ---------------------------------------------------------------------------
// Kernel: per-(group,bucket) partial sums. Grid = NGRP * (NBUCK/256).
// Block (g, quarter) sums its group's ~CPG chunk-hists for 256 buckets.
// All loads/stores coalesced along the bucket axis; wide parallelism.
// ---------------------------------------------------------------------------
__launch_bounds__(256)
__global__ void group_sum_kernel(const unsigned short* __restrict__ gchist,
                                 int* __restrict__ psum, int NCH, int CPG) {
    int g  = blockIdx.x >> 2;                       // group
    int br = ((blockIdx.x & 3) << 8) + threadIdx.x; // bucket
    int c0 = g * CPG, c1 = min(NCH, c0 + CPG);
    int s = 0;
    #pragma unroll 4
    for (int c = c0; c < c1; ++c)
        s += (int)gchist[(size_t)c * NBUCK + br];
    psum[(size_t)g * NBUCK + br] = s;
}

// ---------------------------------------------------------------------------
// Kernel: single-block scan over buckets + groups (small: NGRP values per
// bucket). Thread t owns bucket t: total = sum_g psum[g][t]; exclusive scan
// over buckets -> bbase; then group bases gbase_grp[g][t] = bbase[t] +
// prefix over groups. Also offs[N] = E.
// ---------------------------------------------------------------------------
__launch_bounds__(1024)
__global__ void bucket_scan_kernel(const int* __restrict__ psum,
                                   int* __restrict__ bbase,
                                   int* __restrict__ gbase_grp,
                                   int* __restrict__ offs, int N, int E) {
    __shared__ int s[NBUCK];
    int t = threadIdx.x;
    int v = 0;
    #pragma unroll
    for (int g = 0; g < NGRP; ++g)
        v += psum[(size_t)g * NBUCK + t];
    s[t] = v;
    __syncthreads();
    for (int d = 1; d < NBUCK; d <<= 1) {
        int u = (t >= d) ? s[t - d] : 0;
        __syncthreads();
        s[t] += u;
        __syncthreads();
    }
    int ex = s[t] - v;
    bbase[t] = ex;
    if (t == NBUCK - 1) {
        bbase[NBUCK] = s[t];   // == E
        offs[N] = E;
    }
    int run = ex;
    #pragma unroll
    for (int g = 0; g < NGRP; ++g) {
        gbase_grp[(size_t)g * NBUCK + t] = run;
        run += psum[(size_t)g * NBUCK + t];
    }
}

// ---------------------------------------------------------------------------
// Kernel: per-(chunk,bucket) write bases within each group. Grid like
// group_sum. run = gbase_grp[g][br]; walk the group's chunks.
// ---------------------------------------------------------------------------
__launch_bounds__(256)
__global__ void chunk_base_kernel(const unsigned short* __restrict__ gchist,
                                  const int* __restrict__ gbase_grp,
                                  int* __restrict__ gbase, int NCH, int CPG) {
    int g  = blockIdx.x >> 2;
    int br = ((blockIdx.x & 3) << 8) + threadIdx.x;
    int c0 = g * CPG, c1 = min(NCH, c0 + CPG);
    int run = gbase_grp[(size_t)g * NBUCK + br];
    #pragma unroll 4
    for (int c = c0; c < c1; ++c) {
        gbase[(size_t)c * NBUCK + br] = run;
        run += (int)gchist[(size_t)c * NBUCK + br];
    }
}

// ---------------------------------------------------------------------------
// Binning device body: cursor row comes precomputed from gbase -> single
// pass, LDS atomics only. 8-deep batched. EPB=4096 -> 2 batches/thread.
// Packed word: src | (dst & 127) << 17 (N < 2^17).
// ---------------------------------------------------------------------------
__device__ inline void binning_body(const int* __restrict__ ei, int E, int chunk,
                                    const int* __restrict__ gbase,
                                    unsigned* __restrict__ ebuf, int* lh) {
    int t = threadIdx.x;
    const int* gb = gbase + (size_t)chunk * NBUCK;
    for (int i = t; i < NBUCK; i += 256) lh[i] = gb[i];
    __syncthreads();
    int base = chunk * EPB;
    int lim  = min(E, base + EPB);
    for (int e0 = base + t; e0 < lim; e0 += 2048) {
        int dd[8], ss[8];
        #pragma unroll
        for (int q = 0; q < 8; ++q) {
            int e = e0 + q * 256;
            if (e < lim) { dd[q] = ei[E + e]; ss[q] = ei[e]; } else dd[q] = -1;
        }
        #pragma unroll
        for (int q = 0; q < 8; ++q) {
            if (dd[q] >= 0) {
                int pos = atomicAdd(&lh[dd[q] >> BSH], 1);
                ebuf[pos] = (unsigned)ss[q] | ((unsigned)(dd[q] & (BW - 1)) << 17);
            }
        }
    }
}

__launch_bounds__(256)
__global__ void binning_kernel(const int* __restrict__ ei, int E,
                               const int* __restrict__ gbase, unsigned* __restrict__ ebuf) {
    __shared__ int lh[NBUCK];
    binning_body(ei, E, blockIdx.x, gbase, ebuf, lh);
}

// ---------------------------------------------------------------------------
// Fused kernel: blocks [0, NBIN) do binning (latency-bound, start first);
// blocks [NBIN, NBIN+G1T) do hs_bf16 = bf16(x @ W1): 64-row tile, 4x4 per
// thread. W1 and the 64x64 x-tile staged in LDS (coalesced float4 loads),
// inner loop pure ds_read + FMA.
// ---------------------------------------------------------------------------
__launch_bounds__(256, 4)
__global__ void gemm1_binning_kernel(const float* __restrict__ x, const float* __restrict__ W1,
                                     unsigned short* __restrict__ hsb,
                                     const int* __restrict__ ei, int E,
                                     const int* __restrict__ gbase, unsigned* __restrict__ ebuf,
                                     int N, int NBIN) {
    __shared__ float smem[FIN * FH + 64 * XSTR];   // 33.8 KB: Ws + Xs | lh (4 KB)
    int tid = threadIdx.x;
    if ((int)blockIdx.x < NBIN) {
        binning_body(ei, E, (int)blockIdx.x, gbase, ebuf, (int*)smem);
        return;
    }
    // ---- GEMM phase ----
    float* Ws = smem;                  // [64][64] row-major (k, col)
    float* Xs = smem + FIN * FH;       // [64][XSTR] row-major (row, k), padded
    int rowBase = ((int)blockIdx.x - NBIN) * 64;
    {
        const float4* W14 = (const float4*)W1;
        float4* Ws4 = (float4*)Ws;
        #pragma unroll
        for (int i = tid; i < 1024; i += 256) Ws4[i] = W14[i];
        const float4* x4 = (const float4*)x;
        #pragma unroll
        for (int i = tid; i < 1024; i += 256) {
            int row = i >> 4, kq = i & 15;
            int gr = min(rowBase + row, N - 1);    // clamp: loads never fault
            *(float4*)&Xs[row * XSTR + kq * 4] = x4[(size_t)gr * 16 + kq];
        }
    }
    __syncthreads();
    int cg = tid & 15;                 // col group: cols cg*4..+3
    int rg = tid >> 4;                 // row group: rows rg*4..+3
    int r0 = rowBase + rg * 4;
    float4 acc0 = {0,0,0,0}, acc1 = {0,0,0,0}, acc2 = {0,0,0,0}, acc3 = {0,0,0,0};
    #pragma unroll 2
    for (int kc = 0; kc < 16; ++kc) {
        float4 xa0 = *(const float4*)&Xs[(rg * 4 + 0) * XSTR + kc * 4];
        float4 xa1 = *(const float4*)&Xs[(rg * 4 + 1) * XSTR + kc * 4];
        float4 xa2 = *(const float4*)&Xs[(rg * 4 + 2) * XSTR + kc * 4];
        float4 xa3 = *(const float4*)&Xs[(rg * 4 + 3) * XSTR + kc * 4];
        const float* xa0f = (const float*)&xa0;
        const float* xa1f = (const float*)&xa1;
        const float* xa2f = (const float*)&xa2;
        const float* xa3f = (const float*)&xa3;
        #pragma unroll
        for (int j = 0; j < 4; ++j) {
            float4 wv = *(const float4*)&Ws[(kc * 4 + j) * FH + cg * 4];
            float v0 = xa0f[j], v1 = xa1f[j], v2 = xa2f[j], v3 = xa3f[j];
            acc0.x = fmaf(v0, wv.x, acc0.x); acc0.y = fmaf(v0, wv.y, acc0.y);
            acc0.z = fmaf(v0, wv.z, acc0.z); acc0.w = fmaf(v0, wv.w, acc0.w);
            acc1.x = fmaf(v1, wv.x, acc1.x); acc1.y = fmaf(v1, wv.y, acc1.y);
            acc1.z = fmaf(v1, wv.z, acc1.z); acc1.w = fmaf(v1, wv.w, acc1.w);
            acc2.x = fmaf(v2, wv.x, acc2.x); acc2.y = fmaf(v2, wv.y, acc2.y);
            acc2.z = fmaf(v2, wv.z, acc2.z); acc2.w = fmaf(v2, wv.w, acc2.w);
            acc3.x = fmaf(v3, wv.x, acc3.x); acc3.y = fmaf(v3, wv.y, acc3.y);
            acc3.z = fmaf(v3, wv.z, acc3.z); acc3.w = fmaf(v3, wv.w, acc3.w);
        }
    }
    ushort4* hsb4 = (ushort4*)hsb;
    if (r0 + 0 < N) hsb4[(size_t)(r0 + 0) * 16 + cg] =
        make_ushort4(f2bf(acc0.x), f2bf(acc0.y), f2bf(acc0.z), f2bf(acc0.w));
    if (r0 + 1 < N) hsb4[(size_t)(r0 + 1) * 16 + cg] =
        make_ushort4(f2bf(acc1.x), f2bf(acc1.y), f2bf(acc1.z), f2bf(acc1.w));
    if (r0 + 2 < N) hsb4[(size_t)(r0 + 2) * 16 + cg] =
        make_ushort4(f2bf(acc2.x), f2bf(acc2.y), f2bf(acc2.z), f2bf(acc2.w));
    if (r0 + 3 < N) hsb4[(size_t)(r0 + 3) * 16 + cg] =
        make_ushort4(f2bf(acc3.x), f2bf(acc3.y), f2bf(acc3.z), f2bf(acc3.w));
}

// ---------------------------------------------------------------------------
// Kernel: per-bucket CSR build + dinv + offs. One block per bucket; 8-deep
// batched passes; all csr stores land in the block's own contiguous region.
// ---------------------------------------------------------------------------
__launch_bounds__(256)
__global__ void bucket_csr_kernel(const unsigned* __restrict__ ebuf,
                                  const int* __restrict__ bbase,
                                  int* __restrict__ csr, int* __restrict__ offs,
                                  float* __restrict__ dinv, int N) {
    __shared__ int cnt[BW], sc[BW], cur[BW];
    int t = threadIdx.x;
    int b = blockIdx.x;
    if (t < BW) cnt[t] = 0;
    __syncthreads();
    int beg = bbase[b], end = bbase[b + 1];
    for (int i0 = beg + t; i0 < end; i0 += 2048) {
        unsigned ww[8];
        #pragma unroll
        for (int q = 0; q < 8; ++q) {
            int i = i0 + q * 256;
            ww[q] = (i < end) ? ebuf[i] : 0xFFFFFFFFu;   // valid entries < 2^24
        }
        #pragma unroll
        for (int q = 0; q < 8; ++q)
            if (ww[q] != 0xFFFFFFFFu) atomicAdd(&cnt[ww[q] >> 17], 1);
    }
    __syncthreads();
    if (t < BW) sc[t] = cnt[t];
    __syncthreads();
    for (int d = 1; d < BW; d <<= 1) {
        int u = (t < BW && t >= d) ? sc[t - d] : 0;
        __syncthreads();
        if (t < BW) sc[t] += u;
        __syncthreads();
    }
    int nodeBase = b << BSH;
    if (t < BW) {
        int node = nodeBase + t;
        int ex = beg + sc[t] - cnt[t];
        cur[t] = ex;
        if (node < N) {
            offs[node] = ex;
            dinv[node] = rsqrtf((float)(cnt[t] + 1));
        }
    }
    __syncthreads();
    for (int i0 = beg + t; i0 < end; i0 += 2048) {
        unsigned ww[8];
        #pragma unroll
        for (int q = 0; q < 8; ++q) {
            int i = i0 + q * 256;
            ww[q] = (i < end) ? ebuf[i] : 0xFFFFFFFFu;
        }
        #pragma unroll
        for (int q = 0; q < 8; ++q) {
            if (ww[q] != 0xFFFFFFFFu) {
                int pos = atomicAdd(&cur[ww[q] >> 17], 1);
                csr[pos] = (int)(ww[q] & 0x1FFFF);
            }
        }
    }
}

// ---------------------------------------------------------------------------
// Kernel: layer-1 PULL aggregation (bf16 gathers, 8 in flight, per-src dinv
// scale in-reg) fused with finalize1 + GEMM2; writes hs2 pre-scaled as bf16.
// 16 nodes/block; 16 lanes per node, lane owns one ushort4 chunk (4 feats).
// 8-deep is the measured sweet spot (16-deep forced reg-serialization at
// VGPR=36 and regressed 46->56 us).
// ---------------------------------------------------------------------------
__launch_bounds__(256)
__global__ void agg1_gemm2_kernel(const unsigned short* __restrict__ hsb,
                                  const int* __restrict__ csr,
                                  const int* __restrict__ offs, const float* __restrict__ dinv,
                                  const float* __restrict__ b1, const float* __restrict__ W2,
                                  unsigned short* __restrict__ hs2b, int N) {
    __shared__ float W2s[FH * FO];       // 4 KB
    __shared__ float h1s[16][68];        // 68-float row stride (16B-aligned, non-pow2)
    const ushort4* hs4 = (const ushort4*)hsb;   // 16 ushort4 per row
    int tid = threadIdx.x;
    for (int i = tid; i < FH * FO; i += 256) W2s[i] = W2[i];
    int g = tid >> 4, l = tid & 15;
    int n = blockIdx.x * 16 + g;
    if (n < N) {
        float di_n = dinv[n];
        float4 self = bf4_to_f4(hs4[(size_t)n * 16 + l]);
        float4 acc;
        acc.x = self.x * di_n; acc.y = self.y * di_n;
        acc.z = self.z * di_n; acc.w = self.w * di_n;
        int j = offs[n], end = offs[n + 1];
        for (; j + 7 < end; j += 8) {              // 8 gathers in flight
            int s0 = csr[j],     s1 = csr[j + 1], s2 = csr[j + 2], s3 = csr[j + 3];
            int s4 = csr[j + 4], s5 = csr[j + 5], s6 = csr[j + 6], s7 = csr[j + 7];
            float d0 = dinv[s0], d1 = dinv[s1], d2 = dinv[s2], d3 = dinv[s3];
            float d4 = dinv[s4], d5 = dinv[s5], d6 = dinv[s6], d7 = dinv[s7];
            float4 a0 = bf4_to_f4(hs4[(size_t)s0 * 16 + l]);
            float4 a1 = bf4_to_f4(hs4[(size_t)s1 * 16 + l]);
            float4 a2 = bf4_to_f4(hs4[(size_t)s2 * 16 + l]);
            float4 a3 = bf4_to_f4(hs4[(size_t)s3 * 16 + l]);
            float4 a4 = bf4_to_f4(hs4[(size_t)s4 * 16 + l]);
            float4 a5 = bf4_to_f4(hs4[(size_t)s5 * 16 + l]);
            float4 a6 = bf4_to_f4(hs4[(size_t)s6 * 16 + l]);
            float4 a7 = bf4_to_f4(hs4[(size_t)s7 * 16 + l]);
            acc.x += (fmaf(a0.x, d0, a1.x * d1) + fmaf(a2.x, d2, a3.x * d3))
                   + (fmaf(a4.x, d4, a5.x * d5) + fmaf(a6.x, d6, a7.x * d7));
            acc.y += (fmaf(a0.y, d0, a1.y * d1) + fmaf(a2.y, d2, a3.y * d3))
                   + (fmaf(a4.y, d4, a5.y * d5) + fmaf(a6.y, d6, a7.y * d7));
            acc.z += (fmaf(a0.z, d0, a1.z * d1) + fmaf(a2.z, d2, a3.z * d3))
                   + (fmaf(a4.z, d4, a5.z * d5) + fmaf(a6.z, d6, a7.z * d7));
            acc.w += (fmaf(a0.w, d0, a1.w * d1) + fmaf(a2.w, d2, a3.w * d3))
                   + (fmaf(a4.w, d4, a5.w * d5) + fmaf(a6.w, d6, a7.w * d7));
        }
        for (; j + 1 < end; j += 2) {
            int s0 = csr[j], s1 = csr[j + 1];
            float d0 = dinv[s0], d1 = dinv[s1];
            float4 a0 = bf4_to_f4(hs4[(size_t)s0 * 16 + l]);
            float4 a1 = bf4_to_f4(hs4[(size_t)s1 * 16 + l]);
            acc.x += fmaf(a0.x, d0, a1.x * d1);
            acc.y += fmaf(a0.y, d0, a1.y * d1);
            acc.z += fmaf(a0.z, d0, a1.z * d1);
            acc.w += fmaf(a0.w, d0, a1.w * d1);
        }
        if (j < end) {
            int s0 = csr[j];
            float d0 = dinv[s0];
            float4 a0 = bf4_to_f4(hs4[(size_t)s0 * 16 + l]);
            acc.x = fmaf(a0.x, d0, acc.x); acc.y = fmaf(a0.y, d0, acc.y);
            acc.z = fmaf(a0.z, d0, acc.z); acc.w = fmaf(a0.w, d0, acc.w);
        }
        float4 bb = ((const float4*)b1)[l];
        float4 h;
        h.x = fmaxf(fmaf(di_n, acc.x, bb.x), 0.f);
        h.y = fmaxf(fmaf(di_n, acc.y, bb.y), 0.f);
        h.z = fmaxf(fmaf(di_n, acc.z, bb.z), 0.f);
        h.w = fmaxf(fmaf(di_n, acc.w, bb.w), 0.f);
        *((float4*)&h1s[g][l * 4]) = h;
    }
    __syncthreads();
    int r = tid >> 4, o = tid & 15;     // 16 rows x 16 out-cols
    int n2 = blockIdx.x * 16 + r;
    if (n2 < N) {
        float acc = 0.f;
        #pragma unroll
        for (int jj = 0; jj < FH; ++jj)
            acc = fmaf(h1s[r][jj], W2s[jj * FO + o], acc);
        hs2b[(size_t)n2 * FO + o] = f2bf(acc * dinv[n2]);   // pre-scaled bf16
    }
}

// ---------------------------------------------------------------------------
// Kernel: layer-2 PULL aggregation (8 gathers in flight) + bias + log_softmax.
// hs2b table is 3.2 MB -> fits per-XCD L2; gathers are 2B/lane.
// ---------------------------------------------------------------------------
__launch_bounds__(256)
__global__ void agg2_softmax_kernel(const unsigned short* __restrict__ hs2b,
                                    const int* __restrict__ csr,
                                    const int* __restrict__ offs, const float* __restrict__ dinv,
                                    const float* __restrict__ b2, float* __restrict__ out, int N) {
    int tid = threadIdx.x;
    int g = tid >> 4, o = tid & 15;
    int n = blockIdx.x * 16 + g;
    float v = 0.f;
    if (n < N) {
        float acc = bf2f(hs2b[(size_t)n * 16 + o]);    // self loop (pre-scaled)
        int j = offs[n], end = offs[n + 1];
        for (; j + 7 < end; j += 8) {
            int s0 = csr[j],     s1 = csr[j + 1], s2 = csr[j + 2], s3 = csr[j + 3];
            int s4 = csr[j + 4], s5 = csr[j + 5], s6 = csr[j + 6], s7 = csr[j + 7];
            float t0 = bf2f(hs2b[(size_t)s0 * 16 + o]) + bf2f(hs2b[(size_t)s1 * 16 + o]);
            float t1 = bf2f(hs2b[(size_t)s2 * 16 + o]) + bf2f(hs2b[(size_t)s3 * 16 + o]);
            float t2 = bf2f(hs2b[(size_t)s4 * 16 + o]) + bf2f(hs2b[(size_t)s5 * 16 + o]);
            float t3 = bf2f(hs2b[(size_t)s6 * 16 + o]) + bf2f(hs2b[(size_t)s7 * 16 + o]);
            acc += (t0 + t1) + (t2 + t3);
        }
        for (; j < end; ++j) acc += bf2f(hs2b[(size_t)csr[j] * 16 + o]);
        v = fmaf(dinv[n], acc, b2[o]);
    }
    float m = v;
    #pragma unroll
    for (int s = 8; s >= 1; s >>= 1) m = fmaxf(m, __shfl_xor(m, s, 64));
    float ex = __expf(v - m);
    float sum = ex;
    #pragma unroll
    for (int s = 8; s >= 1; s >>= 1) sum += __shfl_xor(sum, s, 64);
    if (n < N) out[(size_t)n * FO + o] = v - m - __logf(sum);
}

// ---------------------------------------------------------------------------
extern "C" void kernel_launch(void* const* d_in, const int* in_sizes, int n_in,
                              void* d_out, int out_size, void* d_ws, size_t ws_size,
                              hipStream_t stream) {
    const float* x  = (const float*)d_in[0];
    const int*   ei = (const int*)d_in[1];     // int32
    const float* W1 = (const float*)d_in[2];
    const float* b1 = (const float*)d_in[3];
    const float* W2 = (const float*)d_in[4];
    const float* b2 = (const float*)d_in[5];
    float* out = (float*)d_out;

    const int N = in_sizes[0] / FIN;
    const int E = in_sizes[1] / 2;
    const int NCH  = (E + EPB - 1) / EPB;            // hist/binning chunks
    const int CPG  = (NCH + NGRP - 1) / NGRP;        // chunks per scan-group
    const int NB4  = (N + BW - 1) / BW;              // buckets actually used
    const int G1T  = (N + 63) / 64;                  // gemm 64-row tiles
    const int GA   = (N + 15) / 16;                  // agg blocks

    char* ws = (char*)d_ws;
    size_t off = 0;
    auto alloc = [&](size_t bytes) -> void* {
        off = (off + 255) & ~(size_t)255;
        void* p = ws + off;
        off += bytes;
        return p;
    };
    float*          dinv      = (float*)alloc((size_t)N * 4);               //  0.4 MB
    unsigned short* hsb       = (unsigned short*)alloc((size_t)N * FH * 2); // 12.8 MB
    unsigned short* hs2b      = (unsigned short*)alloc((size_t)N * FO * 2); //  3.2 MB
    int*            offs      = (int*)alloc((size_t)(N + 1) * 4);           //  0.4 MB
    int*            bbase     = (int*)alloc((NBUCK + 1) * 4);
    unsigned short* gchist    = (unsigned short*)alloc((size_t)NCH * NBUCK * 2); // 0.8 MB
    int*            gbase     = (int*)alloc((size_t)NCH * NBUCK * 4);       //  1.6 MB
    int*            psum      = (int*)alloc((size_t)NGRP * NBUCK * 4);      //  128 KB
    int*            gbase_grp = (int*)alloc((size_t)NGRP * NBUCK * 4);      //  128 KB
    // ebuf + csr (2*E ints = 12.8 MB): in ws if it fits, else alias the x
    // input buffer (25.6 MB, dead after the gemm phase; harness restores d_in
    // before every launch; ws_size constant -> capture-stable branch).
    unsigned* ebuf;
    int*      csr;
    bool ws_fits = (ws_size >= off + 512 + (size_t)E * 8);
    if (ws_fits) {
        ebuf = (unsigned*)alloc((size_t)E * 4);
        csr  = (int*)     alloc((size_t)E * 4);
    } else {
        ebuf = (unsigned*)x;
        csr  = (int*)x + E;
    }

    hist_kernel<<<NCH, 256, 0, stream>>>(ei, E, gchist);
    group_sum_kernel<<<NGRP * (NBUCK / 256), 256, 0, stream>>>(gchist, psum, NCH, CPG);
    bucket_scan_kernel<<<1, NBUCK, 0, stream>>>(psum, bbase, gbase_grp, offs, N, E);
    chunk_base_kernel<<<NGRP * (NBUCK / 256), 256, 0, stream>>>(gchist, gbase_grp,
                                                                gbase, NCH, CPG);
    if (ws_fits) {
        // Overlap: binning blocks first, gemm blocks backfill.
        gemm1_binning_kernel<<<NCH + G1T, 256, 0, stream>>>(x, W1, hsb, ei, E,
                                                            gbase, ebuf, N, NCH);
    } else {
        // ebuf aliases x: gemm must fully precede binning.
        gemm1_binning_kernel<<<G1T, 256, 0, stream>>>(x, W1, hsb, ei, E,
                                                      gbase, ebuf, N, 0);
        binning_kernel<<<NCH, 256, 0, stream>>>(ei, E, gbase, ebuf);
    }
    bucket_csr_kernel<<<NB4, 256, 0, stream>>>(ebuf, bbase, csr, offs, dinv, N);
    agg1_gemm2_kernel<<<GA, 256, 0, stream>>>(hsb, csr, offs, dinv, b1, W2, hs2b, N);
    agg2_softmax_kernel<<<GA, 256, 0, stream>>>(hs2b, csr, offs, dinv, b2, out, N);
}

// Round 7
// 197.978 us; speedup vs baseline: 1.4791x; 1.0006x over previous
//
#include <hip/hip_runtime.h>

// Feature dims fixed by the problem
constexpr int FIN = 64;   // input features
constexpr int FH  = 64;   // hidden
constexpr int FO  = 16;   // output

// edge_index arrives as int32 (harness integer convention), flat [2][E]:
// src = ei[e], dst = ei[e + E].

// Bucket sort parameters: bucket = dst >> 7 (128 nodes per bucket).
constexpr int BSH      = 7;
constexpr int BW       = 1 << BSH;  // 128 nodes / bucket
constexpr int NBUCK    = 1024;      // covers N up to 131072
// ONE chunk size shared by hist and binning. 4096 edges/chunk -> 391 chunks.
constexpr int EPB      = 4096;
// Hierarchical scan: serial single-block section touches only NGRP values
// per bucket (round-5 lesson: single block streaming 4 MB = 46 us).
constexpr int NGRP     = 32;

// GEMM x-tile LDS stride: 68 floats (pad 64+4) so the 4-row-strided compute
// reads alias only 2-way on banks (2-way is free on CDNA4).
constexpr int XSTR     = 68;

// bf16 helpers (manual RNE; exact expand)
__device__ inline unsigned short f2bf(float f) {
    unsigned u = __float_as_uint(f);
    return (unsigned short)((u + 0x7FFFu + ((u >> 16) & 1u)) >> 16);
}
__device__ inline float bf2f(unsigned short h) {
    return __uint_as_float((unsigned)h << 16);
}
__device__ inline float4 bf4_to_f4(ushort4 u) {
    float4 f;
    f.x = bf2f(u.x); f.y = bf2f(u.y); f.z = bf2f(u.z); f.w = bf2f(u.w);
    return f;
}

// ---------------------------------------------------------------------------
// Kernel: dst-bucket histogram. One block per 4K-edge chunk; 8-deep batched
// loads then 8 LDS-atomic chains. Stores only the per-chunk hist (ushort).
// ---------------------------------------------------------------------------
__launch_bounds__(256)
__global__ void hist_kernel(const int* __restrict__ ei, int E,
                            unsigned short* __restrict__ gchist) {
    __shared__ int lh[NBUCK];
    int t = threadIdx.x;
    for (int i = t; i < NBUCK; i += 256) lh[i] = 0;
    __syncthreads();
    int base = blockIdx.x * EPB;
    int lim  = min(E, base + EPB);
    for (int e0 = base + t; e0 < lim; e0 += 2048) {
        int dd[8];
        #pragma unroll
        for (int q = 0; q < 8; ++q) {
            int e = e0 + q * 256;
            dd[q] = (e < lim) ? ei[E + e] : -1;
        }
        #pragma unroll
        for (int q = 0; q < 8; ++q)
            if (dd[q] >= 0) atomicAdd(&lh[dd[q] >> BSH], 1);
    }
    __syncthreads();
    unsigned short* gh = gchist + (size_t)blockIdx.x * NBUCK;
    for (int b = t; b < NBUCK; b += 256)
        gh[b] = (unsigned short)lh[b];              // c <= EPB=4096, fits ushort
}

// ---------------------------------------------------------------------------
// Kernel: per-(group,bucket) partial sums. Grid = NGRP * (NBUCK/256).
// ---------------------------------------------------------------------------
__launch_bounds__(256)
__global__ void group_sum_kernel(const unsigned short* __restrict__ gchist,
                                 int* __restrict__ psum, int NCH, int CPG) {
    int g  = blockIdx.x >> 2;                       // group
    int br = ((blockIdx.x & 3) << 8) + threadIdx.x; // bucket
    int c0 = g * CPG, c1 = min(NCH, c0 + CPG);
    int s = 0;
    #pragma unroll 4
    for (int c = c0; c < c1; ++c)
        s += (int)gchist[(size_t)c * NBUCK + br];
    psum[(size_t)g * NBUCK + br] = s;
}

// ---------------------------------------------------------------------------
// Kernel: single-block scan over buckets + groups (NGRP values per bucket).
// ---------------------------------------------------------------------------
__launch_bounds__(1024)
__global__ void bucket_scan_kernel(const int* __restrict__ psum,
                                   int* __restrict__ bbase,
                                   int* __restrict__ gbase_grp,
                                   int* __restrict__ offs, int N, int E) {
    __shared__ int s[NBUCK];
    int t = threadIdx.x;
    int v = 0;
    #pragma unroll
    for (int g = 0; g < NGRP; ++g)
        v += psum[(size_t)g * NBUCK + t];
    s[t] = v;
    __syncthreads();
    for (int d = 1; d < NBUCK; d <<= 1) {
        int u = (t >= d) ? s[t - d] : 0;
        __syncthreads();
        s[t] += u;
        __syncthreads();
    }
    int ex = s[t] - v;
    bbase[t] = ex;
    if (t == NBUCK - 1) {
        bbase[NBUCK] = s[t];   // == E
        offs[N] = E;
    }
    int run = ex;
    #pragma unroll
    for (int g = 0; g < NGRP; ++g) {
        gbase_grp[(size_t)g * NBUCK + t] = run;
        run += psum[(size_t)g * NBUCK + t];
    }
}

// ---------------------------------------------------------------------------
// Kernel: per-(chunk,bucket) write bases within each group.
// ---------------------------------------------------------------------------
__launch_bounds__(256)
__global__ void chunk_base_kernel(const unsigned short* __restrict__ gchist,
                                  const int* __restrict__ gbase_grp,
                                  int* __restrict__ gbase, int NCH, int CPG) {
    int g  = blockIdx.x >> 2;
    int br = ((blockIdx.x & 3) << 8) + threadIdx.x;
    int c0 = g * CPG, c1 = min(NCH, c0 + CPG);
    int run = gbase_grp[(size_t)g * NBUCK + br];
    #pragma unroll 4
    for (int c = c0; c < c1; ++c) {
        gbase[(size_t)c * NBUCK + br] = run;
        run += (int)gchist[(size_t)c * NBUCK + br];
    }
}

// ---------------------------------------------------------------------------
// Binning device body: cursor row precomputed from gbase -> single pass,
// LDS atomics only. 8-deep batched. Packed word: src | (dst&127)<<17.
// ---------------------------------------------------------------------------
__device__ inline void binning_body(const int* __restrict__ ei, int E, int chunk,
                                    const int* __restrict__ gbase,
                                    unsigned* __restrict__ ebuf, int* lh) {
    int t = threadIdx.x;
    const int* gb = gbase + (size_t)chunk * NBUCK;
    for (int i = t; i < NBUCK; i += 256) lh[i] = gb[i];
    __syncthreads();
    int base = chunk * EPB;
    int lim  = min(E, base + EPB);
    for (int e0 = base + t; e0 < lim; e0 += 2048) {
        int dd[8], ss[8];
        #pragma unroll
        for (int q = 0; q < 8; ++q) {
            int e = e0 + q * 256;
            if (e < lim) { dd[q] = ei[E + e]; ss[q] = ei[e]; } else dd[q] = -1;
        }
        #pragma unroll
        for (int q = 0; q < 8; ++q) {
            if (dd[q] >= 0) {
                int pos = atomicAdd(&lh[dd[q] >> BSH], 1);
                ebuf[pos] = (unsigned)ss[q] | ((unsigned)(dd[q] & (BW - 1)) << 17);
            }
        }
    }
}

__launch_bounds__(256)
__global__ void binning_kernel(const int* __restrict__ ei, int E,
                               const int* __restrict__ gbase, unsigned* __restrict__ ebuf) {
    __shared__ int lh[NBUCK];
    binning_body(ei, E, blockIdx.x, gbase, ebuf, lh);
}

// Per-j FMA block for the GEMM microkernel (all operands in registers).
#define GEMM_JSTEP(WV, J)                                                    \
    {   float v0 = xa0f[J], v1 = xa1f[J], v2 = xa2f[J], v3 = xa3f[J];        \
        acc0.x = fmaf(v0, WV.x, acc0.x); acc0.y = fmaf(v0, WV.y, acc0.y);    \
        acc0.z = fmaf(v0, WV.z, acc0.z); acc0.w = fmaf(v0, WV.w, acc0.w);    \
        acc1.x = fmaf(v1, WV.x, acc1.x); acc1.y = fmaf(v1, WV.y, acc1.y);    \
        acc1.z = fmaf(v1, WV.z, acc1.z); acc1.w = fmaf(v1, WV.w, acc1.w);    \
        acc2.x = fmaf(v2, WV.x, acc2.x); acc2.y = fmaf(v2, WV.y, acc2.y);    \
        acc2.z = fmaf(v2, WV.z, acc2.z); acc2.w = fmaf(v2, WV.w, acc2.w);    \
        acc3.x = fmaf(v3, WV.x, acc3.x); acc3.y = fmaf(v3, WV.y, acc3.y);    \
        acc3.z = fmaf(v3, WV.z, acc3.z); acc3.w = fmaf(v3, WV.w, acc3.w); }

// ---------------------------------------------------------------------------
// Fused kernel: blocks [0, NBIN) bin; blocks [NBIN, NBIN+G1T) do
// hsb = bf16(x @ W1), 64-row tile, 4x4/thread. KEY CHANGE vs round 6:
// per kc, ALL 8 LDS reads (4 Xs rows + 4 Ws col-quads) are issued into
// NAMED registers before any FMA -- round-2/6 counters showed VGPR=40 and
// VALUBusy 19%: the compiler was serializing read->wait->FMA with ~100 cy
// exposed LDS latency per read. Batching waits once per kc (~120 cy
// amortized over 256 FMAs). VGPR budget rises to ~90, within the 128 cap
// of __launch_bounds__(256,4).
// ---------------------------------------------------------------------------
__launch_bounds__(256, 4)
__global__ void gemm1_binning_kernel(const float* __restrict__ x, const float* __restrict__ W1,
                                     unsigned short* __restrict__ hsb,
                                     const int* __restrict__ ei, int E,
                                     const int* __restrict__ gbase, unsigned* __restrict__ ebuf,
                                     int N, int NBIN) {
    __shared__ float smem[FIN * FH + 64 * XSTR];   // 33.8 KB: Ws + Xs | lh (4 KB)
    int tid = threadIdx.x;
    if ((int)blockIdx.x < NBIN) {
        binning_body(ei, E, (int)blockIdx.x, gbase, ebuf, (int*)smem);
        return;
    }
    // ---- GEMM phase ----
    float* Ws = smem;                  // [64][64] row-major (k, col)
    float* Xs = smem + FIN * FH;       // [64][XSTR] row-major (row, k), padded
    int rowBase = ((int)blockIdx.x - NBIN) * 64;
    {
        const float4* W14 = (const float4*)W1;
        float4* Ws4 = (float4*)Ws;
        #pragma unroll
        for (int i = tid; i < 1024; i += 256) Ws4[i] = W14[i];
        const float4* x4 = (const float4*)x;
        #pragma unroll
        for (int i = tid; i < 1024; i += 256) {
            int row = i >> 4, kq = i & 15;
            int gr = min(rowBase + row, N - 1);    // clamp: loads never fault
            *(float4*)&Xs[row * XSTR + kq * 4] = x4[(size_t)gr * 16 + kq];
        }
    }
    __syncthreads();
    int cg = tid & 15;                 // col group: cols cg*4..+3
    int rg = tid >> 4;                 // row group: rows rg*4..+3
    int r0 = rowBase + rg * 4;
    float4 acc0 = {0,0,0,0}, acc1 = {0,0,0,0}, acc2 = {0,0,0,0}, acc3 = {0,0,0,0};
    #pragma unroll 2
    for (int kc = 0; kc < 16; ++kc) {
        // batch all 8 LDS reads first (single waitcnt), then 256 FMAs
        float4 xa0 = *(const float4*)&Xs[(rg * 4 + 0) * XSTR + kc * 4];
        float4 xa1 = *(const float4*)&Xs[(rg * 4 + 1) * XSTR + kc * 4];
        float4 xa2 = *(const float4*)&Xs[(rg * 4 + 2) * XSTR + kc * 4];
        float4 xa3 = *(const float4*)&Xs[(rg * 4 + 3) * XSTR + kc * 4];
        float4 wv0 = *(const float4*)&Ws[(kc * 4 + 0) * FH + cg * 4];
        float4 wv1 = *(const float4*)&Ws[(kc * 4 + 1) * FH + cg * 4];
        float4 wv2 = *(const float4*)&Ws[(kc * 4 + 2) * FH + cg * 4];
        float4 wv3 = *(const float4*)&Ws[(kc * 4 + 3) * FH + cg * 4];
        const float* xa0f = (const float*)&xa0;
        const float* xa1f = (const float*)&xa1;
        const float* xa2f = (const float*)&xa2;
        const float* xa3f = (const float*)&xa3;
        GEMM_JSTEP(wv0, 0)
        GEMM_JSTEP(wv1, 1)
        GEMM_JSTEP(wv2, 2)
        GEMM_JSTEP(wv3, 3)
    }
    ushort4* hsb4 = (ushort4*)hsb;
    if (r0 + 0 < N) hsb4[(size_t)(r0 + 0) * 16 + cg] =
        make_ushort4(f2bf(acc0.x), f2bf(acc0.y), f2bf(acc0.z), f2bf(acc0.w));
    if (r0 + 1 < N) hsb4[(size_t)(r0 + 1) * 16 + cg] =
        make_ushort4(f2bf(acc1.x), f2bf(acc1.y), f2bf(acc1.z), f2bf(acc1.w));
    if (r0 + 2 < N) hsb4[(size_t)(r0 + 2) * 16 + cg] =
        make_ushort4(f2bf(acc2.x), f2bf(acc2.y), f2bf(acc2.z), f2bf(acc2.w));
    if (r0 + 3 < N) hsb4[(size_t)(r0 + 3) * 16 + cg] =
        make_ushort4(f2bf(acc3.x), f2bf(acc3.y), f2bf(acc3.z), f2bf(acc3.w));
}

// ---------------------------------------------------------------------------
// Kernel: per-bucket CSR build + dinv + offs. One block per bucket; 8-deep
// batched passes; all csr stores land in the block's own contiguous region.
// ---------------------------------------------------------------------------
__launch_bounds__(256)
__global__ void bucket_csr_kernel(const unsigned* __restrict__ ebuf,
                                  const int* __restrict__ bbase,
                                  int* __restrict__ csr, int* __restrict__ offs,
                                  float* __restrict__ dinv, int N) {
    __shared__ int cnt[BW], sc[BW], cur[BW];
    int t = threadIdx.x;
    int b = blockIdx.x;
    if (t < BW) cnt[t] = 0;
    __syncthreads();
    int beg = bbase[b], end = bbase[b + 1];
    for (int i0 = beg + t; i0 < end; i0 += 2048) {
        unsigned ww[8];
        #pragma unroll
        for (int q = 0; q < 8; ++q) {
            int i = i0 + q * 256;
            ww[q] = (i < end) ? ebuf[i] : 0xFFFFFFFFu;   // valid entries < 2^24
        }
        #pragma unroll
        for (int q = 0; q < 8; ++q)
            if (ww[q] != 0xFFFFFFFFu) atomicAdd(&cnt[ww[q] >> 17], 1);
    }
    __syncthreads();
    if (t < BW) sc[t] = cnt[t];
    __syncthreads();
    for (int d = 1; d < BW; d <<= 1) {
        int u = (t < BW && t >= d) ? sc[t - d] : 0;
        __syncthreads();
        if (t < BW) sc[t] += u;
        __syncthreads();
    }
    int nodeBase = b << BSH;
    if (t < BW) {
        int node = nodeBase + t;
        int ex = beg + sc[t] - cnt[t];
        cur[t] = ex;
        if (node < N) {
            offs[node] = ex;
            dinv[node] = rsqrtf((float)(cnt[t] + 1));
        }
    }
    __syncthreads();
    for (int i0 = beg + t; i0 < end; i0 += 2048) {
        unsigned ww[8];
        #pragma unroll
        for (int q = 0; q < 8; ++q) {
            int i = i0 + q * 256;
            ww[q] = (i < end) ? ebuf[i] : 0xFFFFFFFFu;
        }
        #pragma unroll
        for (int q = 0; q < 8; ++q) {
            if (ww[q] != 0xFFFFFFFFu) {
                int pos = atomicAdd(&cur[ww[q] >> 17], 1);
                csr[pos] = (int)(ww[q] & 0x1FFFF);
            }
        }
    }
}

// ---------------------------------------------------------------------------
// Kernel: layer-1 PULL aggregation fused with finalize1 + GEMM2.
// KEY CHANGE vs round 6: csr indices for batch b+1 are prefetched while
// batch b's gathers are in flight -- breaks the serial csr(~250cy) ->
// gather(~600cy) chain down to max() instead of sum.
// ---------------------------------------------------------------------------
__launch_bounds__(256)
__global__ void agg1_gemm2_kernel(const unsigned short* __restrict__ hsb,
                                  const int* __restrict__ csr,
                                  const int* __restrict__ offs, const float* __restrict__ dinv,
                                  const float* __restrict__ b1, const float* __restrict__ W2,
                                  unsigned short* __restrict__ hs2b, int N) {
    __shared__ float W2s[FH * FO];       // 4 KB
    __shared__ float h1s[16][68];        // 68-float row stride (16B-aligned, non-pow2)
    const ushort4* hs4 = (const ushort4*)hsb;   // 16 ushort4 per row
    int tid = threadIdx.x;
    for (int i = tid; i < FH * FO; i += 256) W2s[i] = W2[i];
    int g = tid >> 4, l = tid & 15;
    int n = blockIdx.x * 16 + g;
    if (n < N) {
        float di_n = dinv[n];
        float4 self = bf4_to_f4(hs4[(size_t)n * 16 + l]);
        float4 acc;
        acc.x = self.x * di_n; acc.y = self.y * di_n;
        acc.z = self.z * di_n; acc.w = self.w * di_n;
        int j = offs[n], end = offs[n + 1];
        int nb = (end - j) >> 3;                   // full 8-batches
        if (nb > 0) {
            int sI[8];
            #pragma unroll
            for (int q = 0; q < 8; ++q) sI[q] = csr[j + q];
            for (int b = 0; b < nb; ++b) {
                int jn = j + 8;
                bool more = (b + 1 < nb);
                int sN[8];
                #pragma unroll
                for (int q = 0; q < 8; ++q)        // prefetch next batch's indices
                    sN[q] = more ? csr[jn + q] : 0;
                float d0 = dinv[sI[0]], d1 = dinv[sI[1]], d2 = dinv[sI[2]], d3 = dinv[sI[3]];
                float d4 = dinv[sI[4]], d5 = dinv[sI[5]], d6 = dinv[sI[6]], d7 = dinv[sI[7]];
                float4 a0 = bf4_to_f4(hs4[(size_t)sI[0] * 16 + l]);
                float4 a1 = bf4_to_f4(hs4[(size_t)sI[1] * 16 + l]);
                float4 a2 = bf4_to_f4(hs4[(size_t)sI[2] * 16 + l]);
                float4 a3 = bf4_to_f4(hs4[(size_t)sI[3] * 16 + l]);
                float4 a4 = bf4_to_f4(hs4[(size_t)sI[4] * 16 + l]);
                float4 a5 = bf4_to_f4(hs4[(size_t)sI[5] * 16 + l]);
                float4 a6 = bf4_to_f4(hs4[(size_t)sI[6] * 16 + l]);
                float4 a7 = bf4_to_f4(hs4[(size_t)sI[7] * 16 + l]);
                acc.x += (fmaf(a0.x, d0, a1.x * d1) + fmaf(a2.x, d2, a3.x * d3))
                       + (fmaf(a4.x, d4, a5.x * d5) + fmaf(a6.x, d6, a7.x * d7));
                acc.y += (fmaf(a0.y, d0, a1.y * d1) + fmaf(a2.y, d2, a3.y * d3))
                       + (fmaf(a4.y, d4, a5.y * d5) + fmaf(a6.y, d6, a7.y * d7));
                acc.z += (fmaf(a0.z, d0, a1.z * d1) + fmaf(a2.z, d2, a3.z * d3))
                       + (fmaf(a4.z, d4, a5.z * d5) + fmaf(a6.z, d6, a7.z * d7));
                acc.w += (fmaf(a0.w, d0, a1.w * d1) + fmaf(a2.w, d2, a3.w * d3))
                       + (fmaf(a4.w, d4, a5.w * d5) + fmaf(a6.w, d6, a7.w * d7));
                #pragma unroll
                for (int q = 0; q < 8; ++q) sI[q] = sN[q];
                j = jn;
            }
        }
        for (; j + 1 < end; j += 2) {
            int s0 = csr[j], s1 = csr[j + 1];
            float d0 = dinv[s0], d1 = dinv[s1];
            float4 a0 = bf4_to_f4(hs4[(size_t)s0 * 16 + l]);
            float4 a1 = bf4_to_f4(hs4[(size_t)s1 * 16 + l]);
            acc.x += fmaf(a0.x, d0, a1.x * d1);
            acc.y += fmaf(a0.y, d0, a1.y * d1);
            acc.z += fmaf(a0.z, d0, a1.z * d1);
            acc.w += fmaf(a0.w, d0, a1.w * d1);
        }
        if (j < end) {
            int s0 = csr[j];
            float d0 = dinv[s0];
            float4 a0 = bf4_to_f4(hs4[(size_t)s0 * 16 + l]);
            acc.x = fmaf(a0.x, d0, acc.x); acc.y = fmaf(a0.y, d0, acc.y);
            acc.z = fmaf(a0.z, d0, acc.z); acc.w = fmaf(a0.w, d0, acc.w);
        }
        float4 bb = ((const float4*)b1)[l];
        float4 h;
        h.x = fmaxf(fmaf(di_n, acc.x, bb.x), 0.f);
        h.y = fmaxf(fmaf(di_n, acc.y, bb.y), 0.f);
        h.z = fmaxf(fmaf(di_n, acc.z, bb.z), 0.f);
        h.w = fmaxf(fmaf(di_n, acc.w, bb.w), 0.f);
        *((float4*)&h1s[g][l * 4]) = h;
    }
    __syncthreads();
    int r = tid >> 4, o = tid & 15;     // 16 rows x 16 out-cols
    int n2 = blockIdx.x * 16 + r;
    if (n2 < N) {
        float acc = 0.f;
        #pragma unroll
        for (int jj = 0; jj < FH; ++jj)
            acc = fmaf(h1s[r][jj], W2s[jj * FO + o], acc);
        hs2b[(size_t)n2 * FO + o] = f2bf(acc * dinv[n2]);   // pre-scaled bf16
    }
}

// ---------------------------------------------------------------------------
// Kernel: layer-2 PULL aggregation (8 gathers in flight) + bias + log_softmax.
// hs2b table is 3.2 MB -> fits per-XCD L2; gathers are 2B/lane.
// ---------------------------------------------------------------------------
__launch_bounds__(256)
__global__ void agg2_softmax_kernel(const unsigned short* __restrict__ hs2b,
                                    const int* __restrict__ csr,
                                    const int* __restrict__ offs, const float* __restrict__ dinv,
                                    const float* __restrict__ b2, float* __restrict__ out, int N) {
    int tid = threadIdx.x;
    int g = tid >> 4, o = tid & 15;
    int n = blockIdx.x * 16 + g;
    float v = 0.f;
    if (n < N) {
        float acc = bf2f(hs2b[(size_t)n * 16 + o]);    // self loop (pre-scaled)
        int j = offs[n], end = offs[n + 1];
        for (; j + 7 < end; j += 8) {
            int s0 = csr[j],     s1 = csr[j + 1], s2 = csr[j + 2], s3 = csr[j + 3];
            int s4 = csr[j + 4], s5 = csr[j + 5], s6 = csr[j + 6], s7 = csr[j + 7];
            float t0 = bf2f(hs2b[(size_t)s0 * 16 + o]) + bf2f(hs2b[(size_t)s1 * 16 + o]);
            float t1 = bf2f(hs2b[(size_t)s2 * 16 + o]) + bf2f(hs2b[(size_t)s3 * 16 + o]);
            float t2 = bf2f(hs2b[(size_t)s4 * 16 + o]) + bf2f(hs2b[(size_t)s5 * 16 + o]);
            float t3 = bf2f(hs2b[(size_t)s6 * 16 + o]) + bf2f(hs2b[(size_t)s7 * 16 + o]);
            acc += (t0 + t1) + (t2 + t3);
        }
        for (; j < end; ++j) acc += bf2f(hs2b[(size_t)csr[j] * 16 + o]);
        v = fmaf(dinv[n], acc, b2[o]);
    }
    float m = v;
    #pragma unroll
    for (int s = 8; s >= 1; s >>= 1) m = fmaxf(m, __shfl_xor(m, s, 64));
    float ex = __expf(v - m);
    float sum = ex;
    #pragma unroll
    for (int s = 8; s >= 1; s >>= 1) sum += __shfl_xor(sum, s, 64);
    if (n < N) out[(size_t)n * FO + o] = v - m - __logf(sum);
}

// ---------------------------------------------------------------------------
extern "C" void kernel_launch(void* const* d_in, const int* in_sizes, int n_in,
                              void* d_out, int out_size, void* d_ws, size_t ws_size,
                              hipStream_t stream) {
    const float* x  = (const float*)d_in[0];
    const int*   ei = (const int*)d_in[1];     // int32
    const float* W1 = (const float*)d_in[2];
    const float* b1 = (const float*)d_in[3];
    const float* W2 = (const float*)d_in[4];
    const float* b2 = (const float*)d_in[5];
    float* out = (float*)d_out;

    const int N = in_sizes[0] / FIN;
    const int E = in_sizes[1] / 2;
    const int NCH  = (E + EPB - 1) / EPB;            // hist/binning chunks
    const int CPG  = (NCH + NGRP - 1) / NGRP;        // chunks per scan-group
    const int NB4  = (N + BW - 1) / BW;              // buckets actually used
    const int G1T  = (N + 63) / 64;                  // gemm 64-row tiles
    const int GA   = (N + 15) / 16;                  // agg blocks

    char* ws = (char*)d_ws;
    size_t off = 0;
    auto alloc = [&](size_t bytes) -> void* {
        off = (off + 255) & ~(size_t)255;
        void* p = ws + off;
        off += bytes;
        return p;
    };
    float*          dinv      = (float*)alloc((size_t)N * 4);               //  0.4 MB
    unsigned short* hsb       = (unsigned short*)alloc((size_t)N * FH * 2); // 12.8 MB
    unsigned short* hs2b      = (unsigned short*)alloc((size_t)N * FO * 2); //  3.2 MB
    int*            offs      = (int*)alloc((size_t)(N + 1) * 4);           //  0.4 MB
    int*            bbase     = (int*)alloc((NBUCK + 1) * 4);
    unsigned short* gchist    = (unsigned short*)alloc((size_t)NCH * NBUCK * 2); // 0.8 MB
    int*            gbase     = (int*)alloc((size_t)NCH * NBUCK * 4);       //  1.6 MB
    int*            psum      = (int*)alloc((size_t)NGRP * NBUCK * 4);      //  128 KB
    int*            gbase_grp = (int*)alloc((size_t)NGRP * NBUCK * 4);      //  128 KB
    // ebuf + csr (2*E ints = 12.8 MB): in ws if it fits, else alias the x
    // input buffer (25.6 MB, dead after the gemm phase; harness restores d_in
    // before every launch; ws_size constant -> capture-stable branch).
    unsigned* ebuf;
    int*      csr;
    bool ws_fits = (ws_size >= off + 512 + (size_t)E * 8);
    if (ws_fits) {
        ebuf = (unsigned*)alloc((size_t)E * 4);
        csr  = (int*)     alloc((size_t)E * 4);
    } else {
        ebuf = (unsigned*)x;
        csr  = (int*)x + E;
    }

    hist_kernel<<<NCH, 256, 0, stream>>>(ei, E, gchist);
    group_sum_kernel<<<NGRP * (NBUCK / 256), 256, 0, stream>>>(gchist, psum, NCH, CPG);
    bucket_scan_kernel<<<1, NBUCK, 0, stream>>>(psum, bbase, gbase_grp, offs, N, E);
    chunk_base_kernel<<<NGRP * (NBUCK / 256), 256, 0, stream>>>(gchist, gbase_grp,
                                                                gbase, NCH, CPG);
    if (ws_fits) {
        // Overlap: binning blocks first, gemm blocks backfill.
        gemm1_binning_kernel<<<NCH + G1T, 256, 0, stream>>>(x, W1, hsb, ei, E,
                                                            gbase, ebuf, N, NCH);
    } else {
        // ebuf aliases x: gemm must fully precede binning.
        gemm1_binning_kernel<<<G1T, 256, 0, stream>>>(x, W1, hsb, ei, E,
                                                      gbase, ebuf, N, 0);
        binning_kernel<<<NCH, 256, 0, stream>>>(ei, E, gbase, ebuf);
    }
    bucket_csr_kernel<<<NB4, 256, 0, stream>>>(ebuf, bbase, csr, offs, dinv, N);
    agg1_gemm2_kernel<<<GA, 256, 0, stream>>>(hsb, csr, offs, dinv, b1, W2, hs2b, N);
    agg2_softmax_kernel<<<GA, 256, 0, stream>>>(hs2b, csr, offs, dinv, b2, out, N);
}